// Round 1
// 495.673 us; speedup vs baseline: 1.0976x; 1.0976x over previous
//
#include <hip/hip_runtime.h>
#include <cfloat>

// Problem constants (MoMEAdaptor): B=2,S=1024,H=2048,D=256,R=32,K=4,NDB=100000
#define B_   2
#define S_   1024
#define H_   2048
#define D_   256
#define R_   32
#define K_   4
#define NDB_ 100000

// Only queries (b, t<256) feed the attention (mask j<=i => j<1024 => t<256).
#define TSEL 256
#define NSEL (B_ * TSEL)          // 512 queries that need k-NN

// knn tiling
#define NCHUNK     61             // db chunks
#define CHUNK_ROWS 1664           // 13 tiles * 128
#define TILES      13
#define NT         128            // db rows per tile
#define MT         64             // queries per block
#define KC         64             // fallback K-chunk
#define LSTR       68             // fallback padded LDS stride

#define NEG_INF  (-3.0e38f)
#define IDX_MAX  0x7fffffff

// attention query tile
#define TQ 4

// Workspace layout (bytes). need = 0xA00000 + 51.2MB
#define OFF_Q     0          // 2048*256 f32            (2 MB)
#define OFF_KN    0x200000   // 100000 f32              (400 KB)
#define OFF_PS    0x280000   // 512*61*4 f32
#define OFF_PI    0x300000   // 512*61*4 i32
#define OFF_IDX   0x380000   // 2048 i32
#define OFF_CAND  0x3A0000   // 512*16 i32 candidates
#define OFF_KVT   0x400000   // keys transposed [2][256][1024] f32 (2 MB)
#define OFF_AO    0x600000   // attention out [2048][256] f32 (2 MB)
#define OFF_KVV   0x800000   // values dense [2][1024][256] f32 (2 MB)
#define OFF_DBK16 0xA00000   // bf16 db copy 100000*256*2 = 51.2 MB

typedef unsigned short ushort_t;
typedef unsigned int   uint_t;
typedef __attribute__((ext_vector_type(8)))  __bf16 bf16x8;
typedef __attribute__((ext_vector_type(16))) float  f32x16;

// sorted-insert of (score,idx) into descending top-4; ties -> lower index first
__device__ __forceinline__ void ins4(float sc, int n, float s[4], int id[4]) {
  if (sc > s[3] || (sc == s[3] && n < id[3])) {
    s[3] = sc; id[3] = n;
#pragma unroll
    for (int k = 3; k > 0; --k) {
      if (s[k] > s[k - 1] || (s[k] == s[k - 1] && id[k] < id[k - 1])) {
        float ts = s[k]; s[k] = s[k - 1]; s[k - 1] = ts;
        int ti = id[k]; id[k] = id[k - 1]; id[k - 1] = ti;
      }
    }
  }
}

__device__ __forceinline__ uint_t bfpack(float a, float b) {   // 2x fp32 -> packed bf16 (RNE)
  uint_t ua = __float_as_uint(a), ub = __float_as_uint(b);
  ua = (ua + 0x7fffu + ((ua >> 16) & 1u)) >> 16;
  ub = (ub + 0x7fffu + ((ub >> 16) & 1u)) >> 16;
  return ua | (ub << 16);
}

// ---------------- q = (hidden @ wq_in) @ wq_out,  one block per token ----------------
__global__ __launch_bounds__(256) void k_compute_q(
    const float* __restrict__ hidden, const float* __restrict__ wq_in,
    const float* __restrict__ wq_out, float* __restrict__ q) {
  __shared__ float hrow[H_];
  __shared__ float part[8][R_];
  __shared__ float q1[R_];
  const int m = blockIdx.x;
  const int t = threadIdx.x;
  const float* hp = hidden + (size_t)m * H_;
  ((float4*)hrow)[t]       = ((const float4*)hp)[t];
  ((float4*)hrow)[t + 256] = ((const float4*)hp)[t + 256];
  __syncthreads();
  const int r = t & 31, c = t >> 5;
  float p = 0.f;
#pragma unroll 4
  for (int e = c * 256; e < c * 256 + 256; ++e)
    p = fmaf(hrow[e], wq_in[(size_t)e * R_ + r], p);
  part[c][r] = p;
  __syncthreads();
  if (t < R_) {
    float s = 0.f;
#pragma unroll
    for (int cc = 0; cc < 8; ++cc) s += part[cc][t];
    q1[t] = s;
  }
  __syncthreads();
  float acc = 0.f;
#pragma unroll
  for (int rr = 0; rr < R_; ++rr) acc = fmaf(q1[rr], wq_out[rr * D_ + t], acc);
  q[(size_t)m * D_ + t] = acc;
}

// ---------------- kn[n] = |db_keys[n]|^2 (+ fused bf16 conversion) ----------------
__global__ __launch_bounds__(256) void k_kn_cvt(const float* __restrict__ dbk,
                                               float* __restrict__ kn,
                                               ushort_t* __restrict__ dbk16) {
  const int w = threadIdx.x >> 6, l = threadIdx.x & 63;
  const int n = blockIdx.x * 4 + w;
  if (n >= NDB_) return;
  const float4 v = ((const float4*)(dbk + (size_t)n * D_))[l];
  uint2 p; p.x = bfpack(v.x, v.y); p.y = bfpack(v.z, v.w);
  ((uint2*)(dbk16 + (size_t)n * D_))[l] = p;
  float s = v.x * v.x + v.y * v.y + v.z * v.z + v.w * v.w;
#pragma unroll
  for (int off = 32; off; off >>= 1) s += __shfl_down(s, off);
  if (l == 0) kn[n] = s;
}

// plain kn (fallback path, no bf16 copy)
__global__ __launch_bounds__(256) void k_kn(const float* __restrict__ dbk,
                                            float* __restrict__ kn) {
  const int w = threadIdx.x >> 6, l = threadIdx.x & 63;
  const int n = blockIdx.x * 4 + w;
  if (n >= NDB_) return;
  const float4 v = ((const float4*)(dbk + (size_t)n * D_))[l];
  float s = v.x * v.x + v.y * v.y + v.z * v.z + v.w * v.w;
#pragma unroll
  for (int off = 32; off; off >>= 1) s += __shfl_down(s, off);
  if (l == 0) kn[n] = s;
}

// ---------------- bf16 MFMA knn: per-(qb, chunk) partial top-4 ----------------
// approx score = 2*(q.k)_bf16 - kn_fp32 (verified: picks identical indices as fp32
// at this problem's top-16 margin; final top-4 from exact fp32 rescore anyway).
// Block: 64q x 128n, K=256 in two halves. A resident in LDS (XOR chunk swizzle);
// B via global_load_lds w=16 with swizzle folded into the GLOBAL address (LDS side
// lane-contiguous, m104 rule). Scores overlay B. 64 KB LDS -> 2 blocks/CU.
// Grid: 512 blocks (24 dummies). XCD co-location swizzle: all 8 qb-blocks of a
// chunk share fid%8 -> same XCD (round-robin dispatch) -> chunk data fetched into
// ONE L2 instead of 4-8 -> FETCH_SIZE should drop 202MB -> ~60MB.
__global__ __launch_bounds__(256, 2) void k_knn_mfma(
    const float* __restrict__ q, const ushort_t* __restrict__ dbk16,
    const float* __restrict__ kn, float* __restrict__ pscore,
    int* __restrict__ pidx) {
  __shared__ __align__(16) char smem[65536];
  ushort_t* sA = (ushort_t*)smem;            // 64 rows x 32 chunks x 16B = 32768
  ushort_t* sB = (ushort_t*)(smem + 32768);  // 128 rows x 16 chunks x 16B = 32768
  float*    sS = (float*)(smem + 32768);     // scores [64 m][128 n] overlay on B

  const int fid = blockIdx.x;                // 512 blocks
  const int chunk = (fid & 7) + 8 * ((fid >> 3) & 7);
  const int qb = fid >> 6;                   // 0..7
  if (chunk >= NCHUNK) return;               // 24 dummy blocks

  const int tid = threadIdx.x;
  const int wv = tid >> 6, ln = tid & 63;
  const int lm = ln & 31, lh = ln >> 5;
  const int tx = tid & 15, ty = tid >> 4;
  const int row_base = chunk * CHUNK_ROWS;

  // ---- stage A once: 64 selected q rows -> bf16, swizzled chunks ----
  {
    const int m = tid & 63, cg = tid >> 6;
    const int sq = qb * MT + m;
    const float* qp = q + ((size_t)((sq >> 8) * S_ + (sq & 255))) * D_;
#pragma unroll
    for (int cc = 0; cc < 8; ++cc) {
      const int c = cg * 8 + cc;
      const float4 v0 = *(const float4*)(qp + c * 8);
      const float4 v1 = *(const float4*)(qp + c * 8 + 4);
      uint4 pk;
      pk.x = bfpack(v0.x, v0.y); pk.y = bfpack(v0.z, v0.w);
      pk.z = bfpack(v1.x, v1.y); pk.w = bfpack(v1.z, v1.w);
      *(uint4*)&sA[(m * 32 + (c ^ (m & 7))) * 8] = pk;
    }
  }

  float s4[4][4]; int i4[4][4];
#pragma unroll
  for (int a = 0; a < 4; ++a)
#pragma unroll
    for (int b = 0; b < 4; ++b) { s4[a][b] = NEG_INF; i4[a][b] = IDX_MAX; }

  for (int tile = 0; tile < TILES; ++tile) {
    const int row0 = row_base + tile * NT;
    if (row0 >= NDB_) break;

    f32x16 acc0, acc1;
#pragma unroll
    for (int r = 0; r < 16; ++r) { acc0[r] = 0.f; acc1[r] = 0.f; }

    for (int kh = 0; kh < 2; ++kh) {
      __syncthreads();    // prev consumers of sB/sS done
      // ---- stage B half: wave wv stages rows [wv*32, wv*32+32) ----
      {
        const int n_in = ln >> 4;          // row within 4-row instr group
        const int p    = ln & 15;          // stored chunk position
#pragma unroll
        for (int i = 0; i < 8; ++i) {
          const int nloc = wv * 32 + i * 4 + n_in;
          int krow = row0 + nloc; if (krow >= NDB_) krow = NDB_ - 1;
          const int c = p ^ (nloc & 7);    // global chunk within half
          const ushort_t* gp = dbk16 + (size_t)krow * D_ + (kh * 16 + c) * 8;
          ushort_t* lp = sB + (size_t)(wv * 32 + i * 4) * 128;  // wave-uniform base
          __builtin_amdgcn_global_load_lds(
              (const __attribute__((address_space(1))) void*)gp,
              (__attribute__((address_space(3))) void*)lp, 16, 0, 0);
        }
      }
      __syncthreads();
      // ---- MFMA over this k-half: 8 steps of K=16 ----
      const int nB = wv * 32 + lm;
      const int bswz = nB & 7;
#pragma unroll
      for (int ks = 0; ks < 8; ++ks) {
        const int cA = kh * 16 + ks * 2 + lh;
        const bf16x8 a0 = *(const bf16x8*)&sA[(lm * 32 + (cA ^ (lm & 7))) * 8];
        const bf16x8 a1 = *(const bf16x8*)&sA[((32 + lm) * 32 + (cA ^ (lm & 7))) * 8];
        const bf16x8 bb = *(const bf16x8*)&sB[(nB * 16 + ((ks * 2 + lh) ^ bswz)) * 8];
        acc0 = __builtin_amdgcn_mfma_f32_32x32x16_bf16(a0, bb, acc0, 0, 0, 0);
        acc1 = __builtin_amdgcn_mfma_f32_32x32x16_bf16(a1, bb, acc1, 0, 0, 0);
      }
    }
    __syncthreads();   // all B reads done -> safe to overlay scores

    // ---- write C frags to LDS: sS[m][n] (bank = n%32 = lane, conflict-free) ----
    {
      const int n = (tid >> 6) * 32 + lm;
#pragma unroll
      for (int r = 0; r < 16; ++r) {
        const int mrow = (r & 3) + 8 * (r >> 2) + 4 * lh;
        sS[mrow * 128 + n]        = acc0[r];
        sS[(32 + mrow) * 128 + n] = acc1[r];
      }
    }
    __syncthreads();

    // ---- prefiltered select: thread = 8 n cols x 4 q rows, running top-4 ----
    {
      const int nbase = row0 + tx * 8;
      float knv[8]; int nok[8];
#pragma unroll
      for (int j = 0; j < 8; ++j) {
        nok[j] = (nbase + j < NDB_);
        knv[j] = nok[j] ? kn[nbase + j] : 0.f;
      }
#pragma unroll
      for (int qi = 0; qi < 4; ++qi) {
        const int m = ty * 4 + qi;
        const float4 v0 = *(const float4*)&sS[m * 128 + tx * 8];
        const float4 v1 = *(const float4*)&sS[m * 128 + tx * 8 + 4];
        const float sv[8] = {v0.x, v0.y, v0.z, v0.w, v1.x, v1.y, v1.z, v1.w};
        float v[8];
#pragma unroll
        for (int j = 0; j < 8; ++j)
          v[j] = nok[j] ? fmaf(2.f, sv[j], -knv[j]) : NEG_INF;
        const float mx = fmaxf(fmaxf(fmaxf(v[0], v[1]), fmaxf(v[2], v[3])),
                               fmaxf(fmaxf(v[4], v[5]), fmaxf(v[6], v[7])));
        if (mx >= s4[qi][3]) {
#pragma unroll
          for (int j = 0; j < 8; ++j)
            if (nok[j]) ins4(v[j], nbase + j, s4[qi], i4[qi]);
        }
      }
    }
  }

  // ---- block merge: 64 cand-sets of 4 per query -> top-4 for (query, chunk) ----
  __syncthreads();
  float* cs = (float*)smem;
  int*   ci = (int*)(smem + 64 * 65 * 4);
#pragma unroll
  for (int qi = 0; qi < 4; ++qi)
#pragma unroll
    for (int k = 0; k < 4; ++k) {
      cs[(ty * 4 + qi) * 65 + tx * 4 + k] = s4[qi][k];
      ci[(ty * 4 + qi) * 65 + tx * 4 + k] = i4[qi][k];
    }
  __syncthreads();
  if (tid < 64) {
    float fs[4]; int fi[4];
#pragma unroll
    for (int k = 0; k < 4; ++k) { fs[k] = NEG_INF; fi[k] = IDX_MAX; }
    for (int c = 0; c < 64; ++c)
      ins4(cs[tid * 65 + c], ci[tid * 65 + c], fs, fi);
    const int sq = qb * MT + tid;
    float* po = pscore + ((size_t)sq * NCHUNK + chunk) * 4;
    int*   io = pidx   + ((size_t)sq * NCHUNK + chunk) * 4;
#pragma unroll
    for (int k = 0; k < 4; ++k) { po[k] = fs[k]; io[k] = fi[k]; }
  }
}

// ---------------- fp32 fallback knn (round-1 kernel, used if ws too small) ----------------
__global__ __launch_bounds__(256) void k_knn_partial(
    const float* __restrict__ q, const float* __restrict__ dbk,
    const float* __restrict__ kn, float* __restrict__ pscore,
    int* __restrict__ pidx) {
  __shared__ float smem[3 * KC * LSTR];
  float* sA  = smem;
  float* sB0 = smem + KC * LSTR;
  float* sB1 = smem + 2 * KC * LSTR;
  const int tid = threadIdx.x;
  const int tx = tid & 15, ty = tid >> 4;
  const int chunk = blockIdx.x, qb = blockIdx.y;
  const int arq = tid >> 2;
  const int aqd = (tid & 3) * 4;
  const int brk = tid >> 1;
  const int bh  = tid & 1;
  const int bcol = ((brk >> 3) << 2) | (brk & 3);
  float* sBw = (brk & 4) ? sB1 : sB0;
  const int sq_a = qb * MT + arq;
  const float* qsrc = q + ((size_t)((sq_a >> 8) * S_ + (sq_a & 255))) * D_;
  float s4[4][4]; int i4[4][4];
#pragma unroll
  for (int a = 0; a < 4; ++a)
#pragma unroll
    for (int b = 0; b < 4; ++b) { s4[a][b] = NEG_INF; i4[a][b] = IDX_MAX; }
  const int row_base = chunk * CHUNK_ROWS;
  for (int tile = 0; tile < TILES; ++tile) {
    const int row0 = row_base + tile * NT;
    if (row0 >= NDB_) break;
    int krow = row0 + brk; if (krow >= NDB_) krow = NDB_ - 1;
    const float* ksrc = dbk + (size_t)krow * D_;
    float acc[4][8];
#pragma unroll
    for (int a = 0; a < 4; ++a)
#pragma unroll
      for (int b = 0; b < 8; ++b) acc[a][b] = 0.f;
    for (int kc = 0; kc < 4; ++kc) {
      __syncthreads();
#pragma unroll
      for (int p = 0; p < 4; ++p) {
        const int kkl = p * 16 + aqd;
        const float4 v = *(const float4*)(qsrc + kc * KC + kkl);
        sA[(kkl + 0) * LSTR + arq] = v.x;
        sA[(kkl + 1) * LSTR + arq] = v.y;
        sA[(kkl + 2) * LSTR + arq] = v.z;
        sA[(kkl + 3) * LSTR + arq] = v.w;
      }
#pragma unroll
      for (int p = 0; p < 8; ++p) {
        const int kkl = bh * 32 + p * 4;
        const float4 v = *(const float4*)(ksrc + kc * KC + kkl);
        sBw[(kkl + 0) * LSTR + bcol] = v.x;
        sBw[(kkl + 1) * LSTR + bcol] = v.y;
        sBw[(kkl + 2) * LSTR + bcol] = v.z;
        sBw[(kkl + 3) * LSTR + bcol] = v.w;
      }
      __syncthreads();
#pragma unroll 4
      for (int kk = 0; kk < KC; ++kk) {
        const float4 a  = *(const float4*)&sA [kk * LSTR + ty * 4];
        const float4 b0 = *(const float4*)&sB0[kk * LSTR + tx * 4];
        const float4 b1 = *(const float4*)&sB1[kk * LSTR + tx * 4];
        const float av[4] = {a.x, a.y, a.z, a.w};
        const float bv[8] = {b0.x, b0.y, b0.z, b0.w, b1.x, b1.y, b1.z, b1.w};
#pragma unroll
        for (int qi = 0; qi < 4; ++qi)
#pragma unroll
          for (int nj = 0; nj < 8; ++nj)
            acc[qi][nj] = fmaf(av[qi], bv[nj], acc[qi][nj]);
      }
    }
#pragma unroll
    for (int nj = 0; nj < 8; ++nj) {
      const int n = row0 + tx * 8 + nj;
      if (n < NDB_) {
        const float knj = kn[n];
        ins4(2.f * acc[0][nj] - knj, n, s4[0], i4[0]);
        ins4(2.f * acc[1][nj] - knj, n, s4[1], i4[1]);
        ins4(2.f * acc[2][nj] - knj, n, s4[2], i4[2]);
        ins4(2.f * acc[3][nj] - knj, n, s4[3], i4[3]);
      }
    }
  }
  __syncthreads();
  float* cs = smem;
  int*   ci = (int*)(smem + 64 * 65);
#pragma unroll
  for (int qi = 0; qi < 4; ++qi)
#pragma unroll
    for (int k = 0; k < 4; ++k) {
      cs[(ty * 4 + qi) * 65 + tx * 4 + k] = s4[qi][k];
      ci[(ty * 4 + qi) * 65 + tx * 4 + k] = i4[qi][k];
    }
  __syncthreads();
  if (tid < 64) {
    float fs[4]; int fi[4];
#pragma unroll
    for (int k = 0; k < 4; ++k) { fs[k] = NEG_INF; fi[k] = IDX_MAX; }
    for (int c = 0; c < 64; ++c)
      ins4(cs[tid * 65 + c], ci[tid * 65 + c], fs, fi);
    const int sq = qb * MT + tid;
    float* po = pscore + ((size_t)sq * NCHUNK + chunk) * 4;
    int*   io = pidx   + ((size_t)sq * NCHUNK + chunk) * 4;
#pragma unroll
    for (int k = 0; k < 4; ++k) { po[k] = fs[k]; io[k] = fi[k]; }
  }
}

// ---------------- merge chunk candidates -> sorted global top-R ----------------
template <int RANKS>
__device__ __forceinline__ void merge_top(const float* __restrict__ pscore,
                                          const int* __restrict__ pidx,
                                          int* __restrict__ outp) {
  const int sq = blockIdx.x, l = threadIdx.x;
  float s4[4]; int i4[4];
#pragma unroll
  for (int k = 0; k < 4; ++k) { s4[k] = NEG_INF; i4[k] = IDX_MAX; }
  for (int c = l; c < NCHUNK * 4; c += 64)
    ins4(pscore[(size_t)sq * NCHUNK * 4 + c], pidx[(size_t)sq * NCHUNK * 4 + c], s4, i4);
#pragma unroll
  for (int r = 0; r < RANKS; ++r) {
    float s = s4[0]; int i = i4[0];
#pragma unroll
    for (int off = 32; off; off >>= 1) {
      float so = __shfl_down(s, off); int io = __shfl_down(i, off);
      if (so > s || (so == s && io < i)) { s = so; i = io; }
    }
    const float sw = __shfl(s, 0); const int iw = __shfl(i, 0);
    if (l == 0) outp[sq * RANKS + r] = iw;
    if (s4[0] == sw && i4[0] == iw) {
      s4[0] = s4[1]; i4[0] = i4[1];
      s4[1] = s4[2]; i4[1] = i4[2];
      s4[2] = s4[3]; i4[2] = i4[3];
      s4[3] = NEG_INF; i4[3] = IDX_MAX;
    }
  }
}

__global__ __launch_bounds__(64) void k_knn_merge4(const float* __restrict__ ps,
                                                   const int* __restrict__ pi,
                                                   int* __restrict__ knn_idx) {
  merge_top<4>(ps, pi, knn_idx);
}
__global__ __launch_bounds__(64) void k_knn_merge16(const float* __restrict__ ps,
                                                    const int* __restrict__ pi,
                                                    int* __restrict__ cand) {
  merge_top<16>(ps, pi, cand);
}

// ---------------- exact fp32 rescore of 16 candidates -> final sorted top-4 ----------------
__global__ __launch_bounds__(256) void k_rescore(const float* __restrict__ q,
                                                 const float* __restrict__ dbk,
                                                 const float* __restrict__ kn,
                                                 const int* __restrict__ cand,
                                                 int* __restrict__ knn_idx) {
  __shared__ float scs[16];
  __shared__ int   sci[16];
  const int sq = blockIdx.x, wv = threadIdx.x >> 6, l = threadIdx.x & 63;
  const float* qp = q + ((size_t)((sq >> 8) * S_ + (sq & 255))) * D_;
  const float4 qv = ((const float4*)qp)[l];
  for (int cc = wv; cc < 16; cc += 4) {
    const int n = cand[sq * 16 + cc];
    const float4 kv = ((const float4*)(dbk + (size_t)n * D_))[l];
    float s = qv.x * kv.x + qv.y * kv.y + qv.z * kv.z + qv.w * kv.w;
#pragma unroll
    for (int off = 32; off; off >>= 1) s += __shfl_down(s, off);
    if (l == 0) { scs[cc] = 2.f * s - kn[n]; sci[cc] = n; }
  }
  __syncthreads();
  if (threadIdx.x == 0) {
    float s4[4]; int i4[4];
#pragma unroll
    for (int k = 0; k < 4; ++k) { s4[k] = NEG_INF; i4[k] = IDX_MAX; }
#pragma unroll
    for (int c = 0; c < 16; ++c) ins4(scs[c], sci[c], s4, i4);
#pragma unroll
    for (int k = 0; k < 4; ++k) knn_idx[sq * 4 + k] = i4[k];
  }
}

// -------- gather: keys transposed kvT[b][d][j] + values dense kvV[b][j][d] --------
__global__ __launch_bounds__(256) void k_gather(const float* __restrict__ dbk,
                                                const float* __restrict__ dbv,
                                                const int* __restrict__ knn_idx,
                                                float* __restrict__ kvT,
                                                float* __restrict__ kvV) {
  const int b = blockIdx.x >> 6, j0 = (blockIdx.x & 63) * 16;
  const int w = threadIdx.x >> 6, l = threadIdx.x & 63;
  float* dstT = kvT + (size_t)b * D_ * 1024;
  float* dstV = kvV + (size_t)b * 1024 * D_;
  for (int jj = w; jj < 16; jj += 4) {
    const int j = j0 + jj;
    const int row = knn_idx[b * 1024 + j];
    const float4 kv = ((const float4*)(dbk + (size_t)row * D_))[l];
    dstT[(4 * l + 0) * 1024 + j] = kv.x;
    dstT[(4 * l + 1) * 1024 + j] = kv.y;
    dstT[(4 * l + 2) * 1024 + j] = kv.z;
    dstT[(4 * l + 3) * 1024 + j] = kv.w;
    const float4 vv = ((const float4*)(dbv + (size_t)row * D_))[l];
    ((float4*)(dstV + (size_t)j * D_))[l] = vv;
  }
}

// ---------------- attention: TQ=4 queries per block, K/V reads shared ----------------
// Traffic: 2.1 GB -> ~530 MB. Batch parity == fid&1 == XCD parity (round-robin
// dispatch): each batch's 4 MB kvT+kvV working set stays L2-resident on its 4 XCDs.
// Heavy/light fold pairs long and short causal ranges on adjacent blocks.
// PV split across the 4 waves (j mod 4) + LDS combine to cut serial depth.
template <int CMAX>
__device__ __forceinline__ void qk_dots(const float* __restrict__ kb, int t,
                                        const float (*qrow)[D_], float a[4][TQ]) {
#pragma unroll 2
  for (int d = 0; d < D_; d += 4) {
    float qv[TQ][4];
#pragma unroll
    for (int q = 0; q < TQ; ++q) {
      const float4 v = *(const float4*)&qrow[q][d];
      qv[q][0] = v.x; qv[q][1] = v.y; qv[q][2] = v.z; qv[q][3] = v.w;
    }
#pragma unroll
    for (int dd = 0; dd < 4; ++dd) {
      float kv[CMAX];
#pragma unroll
      for (int c = 0; c < CMAX; ++c)
        kv[c] = kb[(size_t)(d + dd) * 1024 + c * 256 + t];
#pragma unroll
      for (int c = 0; c < CMAX; ++c)
#pragma unroll
        for (int q = 0; q < TQ; ++q)
          a[c][q] = fmaf(qv[q][dd], kv[c], a[c][q]);
    }
  }
}

__global__ __launch_bounds__(256) void k_attn(const float* __restrict__ qarr,
                                              const float* __restrict__ kvT,
                                              const float* __restrict__ kvV,
                                              float* __restrict__ attout) {
  __shared__ float qrow[TQ][D_];       // 4 KB (pre-scaled)
  __shared__ float attw[TQ][1024];     // 16 KB softmax weights
  __shared__ float pvred[4][TQ][D_];   // 16 KB wave-partial PV
  __shared__ float redm[4][TQ], reds[4][TQ];

  const int fid = blockIdx.x;          // 512 blocks
  const int b = fid & 1;               // batch parity == XCD parity
  const int g = fid >> 1;              // 0..255
  const int h = g >> 1;
  const int grp = (g & 1) ? (255 - h) : h;   // heavy/light fold
  const int i0 = grp * TQ;
  const int t = threadIdx.x;
  const int w = t >> 6, l = t & 63;
  const int nkmax = i0 + TQ;           // rows needed (query i0+3 has nk=i0+4)
  const int cmax = (nkmax + 255) >> 8;

  // load TQ q rows, pre-scaled by 1/sqrt(D)=0.0625
  {
    const float4 v = ((const float4*)(qarr + ((size_t)b * S_ + i0 + w) * D_))[l];
    float4 sv;
    sv.x = v.x * 0.0625f; sv.y = v.y * 0.0625f;
    sv.z = v.z * 0.0625f; sv.w = v.w * 0.0625f;
    ((float4*)&qrow[w][0])[l] = sv;
  }
  __syncthreads();

  // ---- QK: thread t owns key column j = c*256+t across up to cmax chunks ----
  const float* kb = kvT + (size_t)b * D_ * 1024;
  float a[4][TQ];
#pragma unroll
  for (int c = 0; c < 4; ++c)
#pragma unroll
    for (int q = 0; q < TQ; ++q) a[c][q] = 0.f;
  switch (cmax) {
    case 1: qk_dots<1>(kb, t, qrow, a); break;
    case 2: qk_dots<2>(kb, t, qrow, a); break;
    case 3: qk_dots<3>(kb, t, qrow, a); break;
    default: qk_dots<4>(kb, t, qrow, a); break;
  }
  // causal mask: key j valid for query i0+q iff j <= i0+q
#pragma unroll
  for (int c = 0; c < 4; ++c)
    if (c < cmax)
#pragma unroll
      for (int q = 0; q < TQ; ++q)
        if (c * 256 + t > i0 + q) a[c][q] = NEG_INF;

  // ---- softmax (per query): max, exp, sum, normalize into attw ----
  float M[TQ];
#pragma unroll
  for (int q = 0; q < TQ; ++q) {
    float m = NEG_INF;
    for (int c = 0; c < cmax; ++c) m = fmaxf(m, a[c][q]);
#pragma unroll
    for (int off = 32; off; off >>= 1) m = fmaxf(m, __shfl_down(m, off));
    if (l == 0) redm[w][q] = m;
  }
  __syncthreads();
#pragma unroll
  for (int q = 0; q < TQ; ++q)
    M[q] = fmaxf(fmaxf(redm[0][q], redm[1][q]), fmaxf(redm[2][q], redm[3][q]));
  float inv[TQ];
#pragma unroll
  for (int q = 0; q < TQ; ++q) {
    float s = 0.f;
    for (int c = 0; c < cmax; ++c) {
      const float p = (a[c][q] > 0.5f * NEG_INF) ? __expf(a[c][q] - M[q]) : 0.f;
      a[c][q] = p; s += p;
    }
#pragma unroll
    for (int off = 32; off; off >>= 1) s += __shfl_down(s, off);
    if (l == 0) reds[w][q] = s;
  }
  __syncthreads();
#pragma unroll
  for (int q = 0; q < TQ; ++q)
    inv[q] = 1.f / (reds[0][q] + reds[1][q] + reds[2][q] + reds[3][q]);
  for (int c = 0; c < cmax; ++c)
#pragma unroll
    for (int q = 0; q < TQ; ++q)
      attw[q][c * 256 + t] = a[c][q] * inv[q];
  __syncthreads();

  // ---- PV: wave w handles rows j == w (mod 4); lane l owns d = 4l..4l+3 ----
  const float* vb = kvV + (size_t)b * 1024 * D_;
  float4 acc[TQ];
#pragma unroll
  for (int q = 0; q < TQ; ++q) acc[q] = make_float4(0.f, 0.f, 0.f, 0.f);
#pragma unroll 2
  for (int j = w; j < nkmax; j += 4) {
    const float4 v = ((const float4*)(vb + (size_t)j * D_))[l];
#pragma unroll
    for (int q = 0; q < TQ; ++q) {
      const float p = attw[q][j];        // LDS broadcast (uniform addr)
      acc[q].x = fmaf(p, v.x, acc[q].x);
      acc[q].y = fmaf(p, v.y, acc[q].y);
      acc[q].z = fmaf(p, v.z, acc[q].z);
      acc[q].w = fmaf(p, v.w, acc[q].w);
    }
  }
#pragma unroll
  for (int q = 0; q < TQ; ++q) ((float4*)&pvred[w][q][0])[l] = acc[q];
  __syncthreads();
  {
    const int q = t >> 6;                // 256 threads = 4 q x 64 lanes
    float4 s = make_float4(0.f, 0.f, 0.f, 0.f);
#pragma unroll
    for (int ww = 0; ww < 4; ++ww) {
      const float4 p = ((const float4*)&pvred[ww][q][0])[l];
      s.x += p.x; s.y += p.y; s.z += p.z; s.w += p.w;
    }
    ((float4*)(attout + ((size_t)b * S_ + i0 + q) * D_))[l] = s;
  }
}

// ---------------- y = (attout @ wv_in) @ wv_out, one block per token ----------------
__global__ __launch_bounds__(256) void k_out(const float* __restrict__ attout,
                                             const float* __restrict__ wv_in,
                                             const float* __restrict__ wv_out,
                                             float* __restrict__ y) {
  __shared__ float row[D_];
  __shared__ float part[8][R_];
  __shared__ float t32[R_];
  const int m = blockIdx.x, t = threadIdx.x;
  row[t] = attout[(size_t)m * D_ + t];
  __syncthreads();
  const int r = t & 31, c = t >> 5;
  float p = 0.f;
#pragma unroll
  for (int d = c * 32; d < c * 32 + 32; ++d)
    p = fmaf(row[d], wv_in[d * R_ + r], p);
  part[c][r] = p;
  __syncthreads();
  if (t < R_) {
    float s = 0.f;
#pragma unroll
    for (int cc = 0; cc < 8; ++cc) s += part[cc][t];
    t32[t] = s;
  }
  __syncthreads();
  for (int hh = t; hh < H_; hh += 256) {
    float a = 0.f;
#pragma unroll
    for (int rr = 0; rr < R_; ++rr) a = fmaf(t32[rr], wv_out[rr * H_ + hh], a);
    y[(size_t)m * H_ + hh] = a;
  }
}

extern "C" void kernel_launch(void* const* d_in, const int* in_sizes, int n_in,
                              void* d_out, int out_size, void* d_ws, size_t ws_size,
                              hipStream_t stream) {
  const float* hidden  = (const float*)d_in[0];
  const float* db_keys = (const float*)d_in[1];
  const float* db_vals = (const float*)d_in[2];
  const float* wq_in   = (const float*)d_in[3];
  const float* wq_out  = (const float*)d_in[4];
  const float* wv_in   = (const float*)d_in[5];
  const float* wv_out  = (const float*)d_in[6];
  float* out = (float*)d_out;

  char* ws = (char*)d_ws;
  float*    q      = (float*)(ws + OFF_Q);
  float*    kn     = (float*)(ws + OFF_KN);
  float*    ps     = (float*)(ws + OFF_PS);
  int*      pi     = (int*)  (ws + OFF_PI);
  int*      idx    = (int*)  (ws + OFF_IDX);
  int*      cand   = (int*)  (ws + OFF_CAND);
  float*    kvT    = (float*)(ws + OFF_KVT);
  float*    attout = (float*)(ws + OFF_AO);
  float*    kvV    = (float*)(ws + OFF_KVV);
  ushort_t* dbk16  = (ushort_t*)(ws + OFF_DBK16);

  const size_t need = (size_t)OFF_DBK16 + (size_t)NDB_ * D_ * 2;

  k_compute_q<<<B_ * S_, 256, 0, stream>>>(hidden, wq_in, wq_out, q);
  if (ws_size >= need) {
    // bf16 MFMA candidate path + exact fp32 rescore
    k_kn_cvt<<<(NDB_ + 3) / 4, 256, 0, stream>>>(db_keys, kn, dbk16);
    k_knn_mfma<<<512, 256, 0, stream>>>(q, dbk16, kn, ps, pi);
    k_knn_merge16<<<NSEL, 64, 0, stream>>>(ps, pi, cand);
    k_rescore<<<NSEL, 256, 0, stream>>>(q, db_keys, kn, cand, idx);
  } else {
    // fp32 fallback
    k_kn<<<(NDB_ + 3) / 4, 256, 0, stream>>>(db_keys, kn);
    k_knn_partial<<<dim3(NCHUNK, 8), 256, 0, stream>>>(q, db_keys, kn, ps, pi);
    k_knn_merge4<<<NSEL, 64, 0, stream>>>(ps, pi, idx);
  }
  k_gather<<<2 * 64, 256, 0, stream>>>(db_keys, db_vals, idx, kvT, kvV);
  k_attn<<<512, 256, 0, stream>>>(q, kvT, kvV, attout);
  k_out<<<B_ * S_, 256, 0, stream>>>(attout, wv_in, wv_out, out);
}

// Round 2
// 451.564 us; speedup vs baseline: 1.2048x; 1.0977x over previous
//
#include <hip/hip_runtime.h>
#include <cfloat>

// Problem constants (MoMEAdaptor): B=2,S=1024,H=2048,D=256,R=32,K=4,NDB=100000
#define B_   2
#define S_   1024
#define H_   2048
#define D_   256
#define R_   32
#define K_   4
#define NDB_ 100000

// Only queries (b, t<256) feed the attention (mask j<=i => j<1024 => t<256).
#define TSEL 256
#define NSEL (B_ * TSEL)          // 512 queries that need k-NN

// knn tiling
#define NCHUNK     61             // db chunks
#define CHUNK_ROWS 1664           // 13 tiles * 128
#define TILES      13
#define NT         128            // db rows per tile
#define MT         64             // queries per block
#define KC         64             // fallback K-chunk
#define LSTR       68             // fallback padded LDS stride

#define NEG_INF  (-3.0e38f)
#define IDX_MAX  0x7fffffff

// attention query tile
#define TQ 4

// Workspace layout (bytes). need = 0xA00000 + 51.2MB
#define OFF_Q     0          // 2048*256 f32            (2 MB)
#define OFF_KN    0x200000   // 100000 f32              (400 KB)
#define OFF_PS    0x280000   // 512*61*4 f32
#define OFF_PI    0x300000   // 512*61*4 i32
#define OFF_IDX   0x380000   // 2048 i32
#define OFF_CAND  0x3A0000   // 512*16 i32 candidates
#define OFF_KVT   0x400000   // keys transposed [2][256][1024] f32 (2 MB)
#define OFF_AO    0x600000   // attention out [2048][256] f32 (2 MB)
#define OFF_KVV   0x800000   // values dense [2][1024][256] f32 (2 MB)
#define OFF_DBK16 0xA00000   // bf16 db copy (MFMA-fragment T-layout) 51.2 MB

typedef unsigned short ushort_t;
typedef unsigned int   uint_t;
typedef __attribute__((ext_vector_type(8)))  __bf16 bf16x8;
typedef __attribute__((ext_vector_type(16))) float  f32x16;

// sorted-insert of (score,idx) into descending top-4; ties -> lower index first
__device__ __forceinline__ void ins4(float sc, int n, float s[4], int id[4]) {
  if (sc > s[3] || (sc == s[3] && n < id[3])) {
    s[3] = sc; id[3] = n;
#pragma unroll
    for (int k = 3; k > 0; --k) {
      if (s[k] > s[k - 1] || (s[k] == s[k - 1] && id[k] < id[k - 1])) {
        float ts = s[k]; s[k] = s[k - 1]; s[k - 1] = ts;
        int ti = id[k]; id[k] = id[k - 1]; id[k - 1] = ti;
      }
    }
  }
}

__device__ __forceinline__ uint_t bfpack(float a, float b) {   // 2x fp32 -> packed bf16 (RNE)
  uint_t ua = __float_as_uint(a), ub = __float_as_uint(b);
  ua = (ua + 0x7fffu + ((ua >> 16) & 1u)) >> 16;
  ub = (ub + 0x7fffu + ((ub >> 16) & 1u)) >> 16;
  return ua | (ub << 16);
}

// ---------------- q = (hidden @ wq_in) @ wq_out,  one block per token ----------------
__global__ __launch_bounds__(256) void k_compute_q(
    const float* __restrict__ hidden, const float* __restrict__ wq_in,
    const float* __restrict__ wq_out, float* __restrict__ q) {
  __shared__ float hrow[H_];
  __shared__ float part[8][R_];
  __shared__ float q1[R_];
  const int m = blockIdx.x;
  const int t = threadIdx.x;
  const float* hp = hidden + (size_t)m * H_;
  ((float4*)hrow)[t]       = ((const float4*)hp)[t];
  ((float4*)hrow)[t + 256] = ((const float4*)hp)[t + 256];
  __syncthreads();
  const int r = t & 31, c = t >> 5;
  float p = 0.f;
#pragma unroll 4
  for (int e = c * 256; e < c * 256 + 256; ++e)
    p = fmaf(hrow[e], wq_in[(size_t)e * R_ + r], p);
  part[c][r] = p;
  __syncthreads();
  if (t < R_) {
    float s = 0.f;
#pragma unroll
    for (int cc = 0; cc < 8; ++cc) s += part[cc][t];
    q1[t] = s;
  }
  __syncthreads();
  float acc = 0.f;
#pragma unroll
  for (int rr = 0; rr < R_; ++rr) acc = fmaf(q1[rr], wq_out[rr * D_ + t], acc);
  q[(size_t)m * D_ + t] = acc;
}

// ------- kn[n] = |db_keys[n]|^2 + bf16 conversion into MFMA-fragment T-layout -------
// T-layout slot: dbk16T[((n/32)*16 + ks)*64 + lane][16B], where for MFMA step ks
// (K=16), lane l supplies A-frag row (l&31) = n%32, k-half (l>>5): k = ks*16+(l>>5)*8.
// So slot(n32, ks, l) holds row (l&31), k-chunk (2*ks + (l>>5)). A wave's
// global_load_dwordx4 in the knn kernel then reads 64 lanes * 16B = 1KB contiguous.
__global__ __launch_bounds__(256) void k_kn_cvtT(const float* __restrict__ dbk,
                                                 float* __restrict__ kn,
                                                 ushort_t* __restrict__ dbk16T) {
  const int n32 = blockIdx.x;            // 0..3124 (NDB_/32 exact)
  const int t = threadIdx.x;
  const int r = t >> 3, tc = t & 7;      // row 0..31, col-group 0..7
  const int n = n32 * 32 + r;
  const float* rp = dbk + (size_t)n * D_ + tc * 32;
  uint4* dst = (uint4*)dbk16T;
  float s = 0.f;
#pragma unroll
  for (int cc = 0; cc < 4; ++cc) {
    const int c = tc * 4 + cc;           // k-chunk of 8 elements
    const float4 a = ((const float4*)rp)[cc * 2];
    const float4 b = ((const float4*)rp)[cc * 2 + 1];
    uint4 pk;
    pk.x = bfpack(a.x, a.y); pk.y = bfpack(a.z, a.w);
    pk.z = bfpack(b.x, b.y); pk.w = bfpack(b.z, b.w);
    dst[(size_t)(n32 * 16 + (c >> 1)) * 64 + (c & 1) * 32 + r] = pk;
    s += a.x*a.x + a.y*a.y + a.z*a.z + a.w*a.w;
    s += b.x*b.x + b.y*b.y + b.z*b.z + b.w*b.w;
  }
  s += __shfl_down(s, 4, 8);
  s += __shfl_down(s, 2, 8);
  s += __shfl_down(s, 1, 8);
  if (tc == 0) kn[n] = s;
}

// plain kn (fallback path, no bf16 copy)
__global__ __launch_bounds__(256) void k_kn(const float* __restrict__ dbk,
                                            float* __restrict__ kn) {
  const int w = threadIdx.x >> 6, l = threadIdx.x & 63;
  const int n = blockIdx.x * 4 + w;
  if (n >= NDB_) return;
  const float4 v = ((const float4*)(dbk + (size_t)n * D_))[l];
  float s = v.x * v.x + v.y * v.y + v.z * v.z + v.w * v.w;
#pragma unroll
  for (int off = 32; off; off >>= 1) s += __shfl_down(s, off);
  if (l == 0) kn[n] = s;
}

// ---------------- bf16 MFMA knn: per-(qb, chunk) partial top-4 ----------------
// approx score = 2*(q.k)_bf16 - kn_fp32; final top-4 from exact fp32 rescore.
// SWAPPED operands: acc = mfma(db_frag, q_frag, acc) -> C[n][query], col=lane&31=query
// (m74/m101-verified C mapping). Each lane owns 16 scores of ONE query -> top-4
// selection is register-local; no C LDS round-trip, no kn re-gather.
// db fragments are register-streamed straight from the T-layout global copy
// (each wave reads only its own 32 rows) -> ZERO barriers in the main loop.
// Queries stay in LDS (32KB, XOR chunk swizzle); kn tile in LDS (6.6KB broadcast).
// Grid: 512 blocks (24 dummies), XCD co-location swizzle (FETCH dedup, r1: 202->27MB).
__global__ __launch_bounds__(256, 2) void k_knn_mfma(
    const float* __restrict__ q, const ushort_t* __restrict__ dbk16T,
    const float* __restrict__ kn, float* __restrict__ pscore,
    int* __restrict__ pidx) {
  __shared__ __align__(16) char smem[32768 + CHUNK_ROWS * 4];
  ushort_t* sA  = (ushort_t*)smem;          // 64 q-rows x 32 chunks x 16B = 32768
  float*    knL = (float*)(smem + 32768);   // kn for this chunk's 1664 rows

  const int fid = blockIdx.x;                // 512 blocks
  const int chunk = (fid & 7) + 8 * ((fid >> 3) & 7);
  const int qb = fid >> 6;                   // 0..7
  if (chunk >= NCHUNK) return;               // 24 dummy blocks

  const int tid = threadIdx.x;
  const int wv = tid >> 6, ln = tid & 63;
  const int lm = ln & 31, lh = ln >> 5;
  const int row_base = chunk * CHUNK_ROWS;

  // ---- stage A once: 64 selected q rows -> bf16, swizzled chunks ----
  {
    const int m = tid & 63, cg = tid >> 6;
    const int sq = qb * MT + m;
    const float* qp = q + ((size_t)((sq >> 8) * S_ + (sq & 255))) * D_;
#pragma unroll
    for (int cc = 0; cc < 8; ++cc) {
      const int c = cg * 8 + cc;
      const float4 v0 = *(const float4*)(qp + c * 8);
      const float4 v1 = *(const float4*)(qp + c * 8 + 4);
      uint4 pk;
      pk.x = bfpack(v0.x, v0.y); pk.y = bfpack(v0.z, v0.w);
      pk.z = bfpack(v1.x, v1.y); pk.w = bfpack(v1.z, v1.w);
      *(uint4*)&sA[(m * 32 + (c ^ (m & 7))) * 8] = pk;
    }
  }
  // ---- stage kn for the whole chunk (clamped; OOB rows masked in select) ----
  for (int j = tid; j < CHUNK_ROWS; j += 256) {
    int rr = row_base + j; if (rr >= NDB_) rr = NDB_ - 1;
    knL[j] = kn[rr];
  }
  __syncthreads();   // the ONLY barrier before the final merge

  // per-lane running top-4: acc0 -> query lm, acc1 -> query 32+lm
  float s40[4], s41[4]; int i40[4], i41[4];
#pragma unroll
  for (int k = 0; k < 4; ++k) {
    s40[k] = NEG_INF; i40[k] = IDX_MAX;
    s41[k] = NEG_INF; i41[k] = IDX_MAX;
  }

  const int sw = lm & 7;
  const int abase0 = lm * 32;          // chunk-slot base, query row lm
  const int abase1 = (32 + lm) * 32;   // query row 32+lm (same swizzle: (32+lm)&7==sw)
  const int nbase = wv * 32 + 4 * lh;  // this lane's n_loc base within the tile

  for (int tile = 0; tile < TILES; ++tile) {
    const int row0 = row_base + tile * NT;
    if (row0 >= NDB_) break;
    const int nw = row0 + wv * 32;     // wave's 32-row block (32-aligned)
    if (nw >= NDB_) continue;          // wave-uniform; NDB_ is a multiple of 32

    f32x16 acc0, acc1;
#pragma unroll
    for (int r = 0; r < 16; ++r) { acc0[r] = 0.f; acc1[r] = 0.f; }

    // lane's fragment stream: 16 steps x 1KB coalesced wave reads
    const ushort_t* gw = dbk16T + (size_t)(nw >> 5) * 8192 + (size_t)ln * 8;
#pragma unroll
    for (int ks = 0; ks < 16; ++ks) {
      const bf16x8 bb = *(const bf16x8*)(gw + ks * 512);
      const int cs = (2 * ks + lh) ^ sw;
      const bf16x8 a0 = *(const bf16x8*)&sA[(abase0 + cs) * 8];
      const bf16x8 a1 = *(const bf16x8*)&sA[(abase1 + cs) * 8];
      acc0 = __builtin_amdgcn_mfma_f32_32x32x16_bf16(bb, a0, acc0, 0, 0, 0);
      acc1 = __builtin_amdgcn_mfma_f32_32x32x16_bf16(bb, a1, acc1, 0, 0, 0);
    }

    // ---- register select: lane's 16 n-rows for its two queries ----
#pragma unroll
    for (int g = 0; g < 4; ++g) {
      float v0[4], v1[4]; int nn[4];
#pragma unroll
      for (int j = 0; j < 4; ++j) {
        const int r = g * 4 + j;
        const int off = (r & 3) + 8 * (r >> 2);    // compile-time
        const int nloc = nbase + off;
        const float knv = knL[tile * 128 + nloc];  // LDS broadcast
        const int n = row0 + nloc;
        nn[j] = n;
        const float x0 = fmaf(2.f, acc0[r], -knv);
        const float x1 = fmaf(2.f, acc1[r], -knv);
        const bool ok = n < NDB_;
        v0[j] = ok ? x0 : NEG_INF;
        v1[j] = ok ? x1 : NEG_INF;
      }
      const float m0 = fmaxf(fmaxf(v0[0], v0[1]), fmaxf(v0[2], v0[3]));
      if (m0 >= s40[3]) {
#pragma unroll
        for (int j = 0; j < 4; ++j) ins4(v0[j], nn[j], s40, i40);
      }
      const float m1 = fmaxf(fmaxf(v1[0], v1[1]), fmaxf(v1[2], v1[3]));
      if (m1 >= s41[3]) {
#pragma unroll
        for (int j = 0; j < 4; ++j) ins4(v1[j], nn[j], s41, i41);
      }
    }
  }

  // ---- merge: 8 partial sets per query (4 waves x 2 k-halves) -> top-4 ----
  __syncthreads();
  float* cs = (float*)smem;                 // 64 q x 8 sets x 4 = 8KB
  int*   ci = (int*)(smem + 8192);          // 8KB
  {
    const int st = wv * 2 + lh;
#pragma unroll
    for (int k = 0; k < 4; ++k) {
      cs[(lm * 8 + st) * 4 + k]        = s40[k];
      ci[(lm * 8 + st) * 4 + k]        = i40[k];
      cs[((32 + lm) * 8 + st) * 4 + k] = s41[k];
      ci[((32 + lm) * 8 + st) * 4 + k] = i41[k];
    }
  }
  __syncthreads();
  if (tid < 64) {
    float fs[4]; int fi[4];
#pragma unroll
    for (int k = 0; k < 4; ++k) { fs[k] = NEG_INF; fi[k] = IDX_MAX; }
    for (int c = 0; c < 32; ++c)
      ins4(cs[tid * 32 + c], ci[tid * 32 + c], fs, fi);
    const int sq = qb * MT + tid;
    float* po = pscore + ((size_t)sq * NCHUNK + chunk) * 4;
    int*   io = pidx   + ((size_t)sq * NCHUNK + chunk) * 4;
#pragma unroll
    for (int k = 0; k < 4; ++k) { po[k] = fs[k]; io[k] = fi[k]; }
  }
}

// ---------------- fp32 fallback knn (round-1 kernel, used if ws too small) ----------------
__global__ __launch_bounds__(256) void k_knn_partial(
    const float* __restrict__ q, const float* __restrict__ dbk,
    const float* __restrict__ kn, float* __restrict__ pscore,
    int* __restrict__ pidx) {
  __shared__ float smem[3 * KC * LSTR];
  float* sA  = smem;
  float* sB0 = smem + KC * LSTR;
  float* sB1 = smem + 2 * KC * LSTR;
  const int tid = threadIdx.x;
  const int tx = tid & 15, ty = tid >> 4;
  const int chunk = blockIdx.x, qb = blockIdx.y;
  const int arq = tid >> 2;
  const int aqd = (tid & 3) * 4;
  const int brk = tid >> 1;
  const int bh  = tid & 1;
  const int bcol = ((brk >> 3) << 2) | (brk & 3);
  float* sBw = (brk & 4) ? sB1 : sB0;
  const int sq_a = qb * MT + arq;
  const float* qsrc = q + ((size_t)((sq_a >> 8) * S_ + (sq_a & 255))) * D_;
  float s4[4][4]; int i4[4][4];
#pragma unroll
  for (int a = 0; a < 4; ++a)
#pragma unroll
    for (int b = 0; b < 4; ++b) { s4[a][b] = NEG_INF; i4[a][b] = IDX_MAX; }
  const int row_base = chunk * CHUNK_ROWS;
  for (int tile = 0; tile < TILES; ++tile) {
    const int row0 = row_base + tile * NT;
    if (row0 >= NDB_) break;
    int krow = row0 + brk; if (krow >= NDB_) krow = NDB_ - 1;
    const float* ksrc = dbk + (size_t)krow * D_;
    float acc[4][8];
#pragma unroll
    for (int a = 0; a < 4; ++a)
#pragma unroll
      for (int b = 0; b < 8; ++b) acc[a][b] = 0.f;
    for (int kc = 0; kc < 4; ++kc) {
      __syncthreads();
#pragma unroll
      for (int p = 0; p < 4; ++p) {
        const int kkl = p * 16 + aqd;
        const float4 v = *(const float4*)(qsrc + kc * KC + kkl);
        sA[(kkl + 0) * LSTR + arq] = v.x;
        sA[(kkl + 1) * LSTR + arq] = v.y;
        sA[(kkl + 2) * LSTR + arq] = v.z;
        sA[(kkl + 3) * LSTR + arq] = v.w;
      }
#pragma unroll
      for (int p = 0; p < 8; ++p) {
        const int kkl = bh * 32 + p * 4;
        const float4 v = *(const float4*)(ksrc + kc * KC + kkl);
        sBw[(kkl + 0) * LSTR + bcol] = v.x;
        sBw[(kkl + 1) * LSTR + bcol] = v.y;
        sBw[(kkl + 2) * LSTR + bcol] = v.z;
        sBw[(kkl + 3) * LSTR + bcol] = v.w;
      }
      __syncthreads();
#pragma unroll 4
      for (int kk = 0; kk < KC; ++kk) {
        const float4 a  = *(const float4*)&sA [kk * LSTR + ty * 4];
        const float4 b0 = *(const float4*)&sB0[kk * LSTR + tx * 4];
        const float4 b1 = *(const float4*)&sB1[kk * LSTR + tx * 4];
        const float av[4] = {a.x, a.y, a.z, a.w};
        const float bv[8] = {b0.x, b0.y, b0.z, b0.w, b1.x, b1.y, b1.z, b1.w};
#pragma unroll
        for (int qi = 0; qi < 4; ++qi)
#pragma unroll
          for (int nj = 0; nj < 8; ++nj)
            acc[qi][nj] = fmaf(av[qi], bv[nj], acc[qi][nj]);
      }
    }
#pragma unroll
    for (int nj = 0; nj < 8; ++nj) {
      const int n = row0 + tx * 8 + nj;
      if (n < NDB_) {
        const float knj = kn[n];
        ins4(2.f * acc[0][nj] - knj, n, s4[0], i4[0]);
        ins4(2.f * acc[1][nj] - knj, n, s4[1], i4[1]);
        ins4(2.f * acc[2][nj] - knj, n, s4[2], i4[2]);
        ins4(2.f * acc[3][nj] - knj, n, s4[3], i4[3]);
      }
    }
  }
  __syncthreads();
  float* cs = smem;
  int*   ci = (int*)(smem + 64 * 65);
#pragma unroll
  for (int qi = 0; qi < 4; ++qi)
#pragma unroll
    for (int k = 0; k < 4; ++k) {
      cs[(ty * 4 + qi) * 65 + tx * 4 + k] = s4[qi][k];
      ci[(ty * 4 + qi) * 65 + tx * 4 + k] = i4[qi][k];
    }
  __syncthreads();
  if (tid < 64) {
    float fs[4]; int fi[4];
#pragma unroll
    for (int k = 0; k < 4; ++k) { fs[k] = NEG_INF; fi[k] = IDX_MAX; }
    for (int c = 0; c < 64; ++c)
      ins4(cs[tid * 65 + c], ci[tid * 65 + c], fs, fi);
    const int sq = qb * MT + tid;
    float* po = pscore + ((size_t)sq * NCHUNK + chunk) * 4;
    int*   io = pidx   + ((size_t)sq * NCHUNK + chunk) * 4;
#pragma unroll
    for (int k = 0; k < 4; ++k) { po[k] = fs[k]; io[k] = fi[k]; }
  }
}

// ---------------- merge chunk candidates -> sorted global top-R ----------------
template <int RANKS>
__device__ __forceinline__ void merge_top(const float* __restrict__ pscore,
                                          const int* __restrict__ pidx,
                                          int* __restrict__ outp) {
  const int sq = blockIdx.x, l = threadIdx.x;
  float s4[4]; int i4[4];
#pragma unroll
  for (int k = 0; k < 4; ++k) { s4[k] = NEG_INF; i4[k] = IDX_MAX; }
  for (int c = l; c < NCHUNK * 4; c += 64)
    ins4(pscore[(size_t)sq * NCHUNK * 4 + c], pidx[(size_t)sq * NCHUNK * 4 + c], s4, i4);
#pragma unroll
  for (int r = 0; r < RANKS; ++r) {
    float s = s4[0]; int i = i4[0];
#pragma unroll
    for (int off = 32; off; off >>= 1) {
      float so = __shfl_down(s, off); int io = __shfl_down(i, off);
      if (so > s || (so == s && io < i)) { s = so; i = io; }
    }
    const float sw = __shfl(s, 0); const int iw = __shfl(i, 0);
    if (l == 0) outp[sq * RANKS + r] = iw;
    if (s4[0] == sw && i4[0] == iw) {
      s4[0] = s4[1]; i4[0] = i4[1];
      s4[1] = s4[2]; i4[1] = i4[2];
      s4[2] = s4[3]; i4[2] = i4[3];
      s4[3] = NEG_INF; i4[3] = IDX_MAX;
    }
  }
}

__global__ __launch_bounds__(64) void k_knn_merge4(const float* __restrict__ ps,
                                                   const int* __restrict__ pi,
                                                   int* __restrict__ knn_idx) {
  merge_top<4>(ps, pi, knn_idx);
}
__global__ __launch_bounds__(64) void k_knn_merge16(const float* __restrict__ ps,
                                                    const int* __restrict__ pi,
                                                    int* __restrict__ cand) {
  merge_top<16>(ps, pi, cand);
}

// ---------------- exact fp32 rescore of 16 candidates -> final sorted top-4 ----------------
__global__ __launch_bounds__(256) void k_rescore(const float* __restrict__ q,
                                                 const float* __restrict__ dbk,
                                                 const float* __restrict__ kn,
                                                 const int* __restrict__ cand,
                                                 int* __restrict__ knn_idx) {
  __shared__ float scs[16];
  __shared__ int   sci[16];
  const int sq = blockIdx.x, wv = threadIdx.x >> 6, l = threadIdx.x & 63;
  const float* qp = q + ((size_t)((sq >> 8) * S_ + (sq & 255))) * D_;
  const float4 qv = ((const float4*)qp)[l];
  for (int cc = wv; cc < 16; cc += 4) {
    const int n = cand[sq * 16 + cc];
    const float4 kv = ((const float4*)(dbk + (size_t)n * D_))[l];
    float s = qv.x * kv.x + qv.y * kv.y + qv.z * kv.z + qv.w * kv.w;
#pragma unroll
    for (int off = 32; off; off >>= 1) s += __shfl_down(s, off);
    if (l == 0) { scs[cc] = 2.f * s - kn[n]; sci[cc] = n; }
  }
  __syncthreads();
  if (threadIdx.x == 0) {
    float s4[4]; int i4[4];
#pragma unroll
    for (int k = 0; k < 4; ++k) { s4[k] = NEG_INF; i4[k] = IDX_MAX; }
#pragma unroll
    for (int c = 0; c < 16; ++c) ins4(scs[c], sci[c], s4, i4);
#pragma unroll
    for (int k = 0; k < 4; ++k) knn_idx[sq * 4 + k] = i4[k];
  }
}

// -------- gather: keys transposed kvT[b][d][j] + values dense kvV[b][j][d] --------
__global__ __launch_bounds__(256) void k_gather(const float* __restrict__ dbk,
                                                const float* __restrict__ dbv,
                                                const int* __restrict__ knn_idx,
                                                float* __restrict__ kvT,
                                                float* __restrict__ kvV) {
  const int b = blockIdx.x >> 6, j0 = (blockIdx.x & 63) * 16;
  const int w = threadIdx.x >> 6, l = threadIdx.x & 63;
  float* dstT = kvT + (size_t)b * D_ * 1024;
  float* dstV = kvV + (size_t)b * 1024 * D_;
  for (int jj = w; jj < 16; jj += 4) {
    const int j = j0 + jj;
    const int row = knn_idx[b * 1024 + j];
    const float4 kv = ((const float4*)(dbk + (size_t)row * D_))[l];
    dstT[(4 * l + 0) * 1024 + j] = kv.x;
    dstT[(4 * l + 1) * 1024 + j] = kv.y;
    dstT[(4 * l + 2) * 1024 + j] = kv.z;
    dstT[(4 * l + 3) * 1024 + j] = kv.w;
    const float4 vv = ((const float4*)(dbv + (size_t)row * D_))[l];
    ((float4*)(dstV + (size_t)j * D_))[l] = vv;
  }
}

// ---------------- attention: TQ=4 queries per block, K/V reads shared ----------------
template <int CMAX>
__device__ __forceinline__ void qk_dots(const float* __restrict__ kb, int t,
                                        const float (*qrow)[D_], float a[4][TQ]) {
#pragma unroll 2
  for (int d = 0; d < D_; d += 4) {
    float qv[TQ][4];
#pragma unroll
    for (int q = 0; q < TQ; ++q) {
      const float4 v = *(const float4*)&qrow[q][d];
      qv[q][0] = v.x; qv[q][1] = v.y; qv[q][2] = v.z; qv[q][3] = v.w;
    }
#pragma unroll
    for (int dd = 0; dd < 4; ++dd) {
      float kv[CMAX];
#pragma unroll
      for (int c = 0; c < CMAX; ++c)
        kv[c] = kb[(size_t)(d + dd) * 1024 + c * 256 + t];
#pragma unroll
      for (int c = 0; c < CMAX; ++c)
#pragma unroll
        for (int q = 0; q < TQ; ++q)
          a[c][q] = fmaf(qv[q][dd], kv[c], a[c][q]);
    }
  }
}

__global__ __launch_bounds__(256) void k_attn(const float* __restrict__ qarr,
                                              const float* __restrict__ kvT,
                                              const float* __restrict__ kvV,
                                              float* __restrict__ attout) {
  __shared__ float qrow[TQ][D_];       // 4 KB (pre-scaled)
  __shared__ float attw[TQ][1024];     // 16 KB softmax weights
  __shared__ float pvred[4][TQ][D_];   // 16 KB wave-partial PV
  __shared__ float redm[4][TQ], reds[4][TQ];

  const int fid = blockIdx.x;          // 512 blocks
  const int b = fid & 1;               // batch parity == XCD parity
  const int g = fid >> 1;              // 0..255
  const int h = g >> 1;
  const int grp = (g & 1) ? (255 - h) : h;   // heavy/light fold
  const int i0 = grp * TQ;
  const int t = threadIdx.x;
  const int w = t >> 6, l = t & 63;
  const int nkmax = i0 + TQ;           // rows needed (query i0+3 has nk=i0+4)
  const int cmax = (nkmax + 255) >> 8;

  // load TQ q rows, pre-scaled by 1/sqrt(D)=0.0625
  {
    const float4 v = ((const float4*)(qarr + ((size_t)b * S_ + i0 + w) * D_))[l];
    float4 sv;
    sv.x = v.x * 0.0625f; sv.y = v.y * 0.0625f;
    sv.z = v.z * 0.0625f; sv.w = v.w * 0.0625f;
    ((float4*)&qrow[w][0])[l] = sv;
  }
  __syncthreads();

  // ---- QK: thread t owns key column j = c*256+t across up to cmax chunks ----
  const float* kb = kvT + (size_t)b * D_ * 1024;
  float a[4][TQ];
#pragma unroll
  for (int c = 0; c < 4; ++c)
#pragma unroll
    for (int q = 0; q < TQ; ++q) a[c][q] = 0.f;
  switch (cmax) {
    case 1: qk_dots<1>(kb, t, qrow, a); break;
    case 2: qk_dots<2>(kb, t, qrow, a); break;
    case 3: qk_dots<3>(kb, t, qrow, a); break;
    default: qk_dots<4>(kb, t, qrow, a); break;
  }
  // causal mask: key j valid for query i0+q iff j <= i0+q
#pragma unroll
  for (int c = 0; c < 4; ++c)
    if (c < cmax)
#pragma unroll
      for (int q = 0; q < TQ; ++q)
        if (c * 256 + t > i0 + q) a[c][q] = NEG_INF;

  // ---- softmax (per query): max, exp, sum, normalize into attw ----
  float M[TQ];
#pragma unroll
  for (int q = 0; q < TQ; ++q) {
    float m = NEG_INF;
    for (int c = 0; c < cmax; ++c) m = fmaxf(m, a[c][q]);
#pragma unroll
    for (int off = 32; off; off >>= 1) m = fmaxf(m, __shfl_down(m, off));
    if (l == 0) redm[w][q] = m;
  }
  __syncthreads();
#pragma unroll
  for (int q = 0; q < TQ; ++q)
    M[q] = fmaxf(fmaxf(redm[0][q], redm[1][q]), fmaxf(redm[2][q], redm[3][q]));
  float inv[TQ];
#pragma unroll
  for (int q = 0; q < TQ; ++q) {
    float s = 0.f;
    for (int c = 0; c < cmax; ++c) {
      const float p = (a[c][q] > 0.5f * NEG_INF) ? __expf(a[c][q] - M[q]) : 0.f;
      a[c][q] = p; s += p;
    }
#pragma unroll
    for (int off = 32; off; off >>= 1) s += __shfl_down(s, off);
    if (l == 0) reds[w][q] = s;
  }
  __syncthreads();
#pragma unroll
  for (int q = 0; q < TQ; ++q)
    inv[q] = 1.f / (reds[0][q] + reds[1][q] + reds[2][q] + reds[3][q]);
  for (int c = 0; c < cmax; ++c)
#pragma unroll
    for (int q = 0; q < TQ; ++q)
      attw[q][c * 256 + t] = a[c][q] * inv[q];
  __syncthreads();

  // ---- PV: wave w handles rows j == w (mod 4); lane l owns d = 4l..4l+3 ----
  const float* vb = kvV + (size_t)b * 1024 * D_;
  float4 acc[TQ];
#pragma unroll
  for (int q = 0; q < TQ; ++q) acc[q] = make_float4(0.f, 0.f, 0.f, 0.f);
#pragma unroll 2
  for (int j = w; j < nkmax; j += 4) {
    const float4 v = ((const float4*)(vb + (size_t)j * D_))[l];
#pragma unroll
    for (int q = 0; q < TQ; ++q) {
      const float p = attw[q][j];        // LDS broadcast (uniform addr)
      acc[q].x = fmaf(p, v.x, acc[q].x);
      acc[q].y = fmaf(p, v.y, acc[q].y);
      acc[q].z = fmaf(p, v.z, acc[q].z);
      acc[q].w = fmaf(p, v.w, acc[q].w);
    }
  }
#pragma unroll
  for (int q = 0; q < TQ; ++q) ((float4*)&pvred[w][q][0])[l] = acc[q];
  __syncthreads();
  {
    const int q = t >> 6;                // 256 threads = 4 q x 64 lanes
    float4 s = make_float4(0.f, 0.f, 0.f, 0.f);
#pragma unroll
    for (int ww = 0; ww < 4; ++ww) {
      const float4 p = ((const float4*)&pvred[ww][q][0])[l];
      s.x += p.x; s.y += p.y; s.z += p.z; s.w += p.w;
    }
    ((float4*)(attout + ((size_t)b * S_ + i0 + q) * D_))[l] = s;
  }
}

// ---------------- y = (attout @ wv_in) @ wv_out, one block per token ----------------
__global__ __launch_bounds__(256) void k_out(const float* __restrict__ attout,
                                             const float* __restrict__ wv_in,
                                             const float* __restrict__ wv_out,
                                             float* __restrict__ y) {
  __shared__ float row[D_];
  __shared__ float part[8][R_];
  __shared__ float t32[R_];
  const int m = blockIdx.x, t = threadIdx.x;
  row[t] = attout[(size_t)m * D_ + t];
  __syncthreads();
  const int r = t & 31, c = t >> 5;
  float p = 0.f;
#pragma unroll
  for (int d = c * 32; d < c * 32 + 32; ++d)
    p = fmaf(row[d], wv_in[d * R_ + r], p);
  part[c][r] = p;
  __syncthreads();
  if (t < R_) {
    float s = 0.f;
#pragma unroll
    for (int cc = 0; cc < 8; ++cc) s += part[cc][t];
    t32[t] = s;
  }
  __syncthreads();
  for (int hh = t; hh < H_; hh += 256) {
    float a = 0.f;
#pragma unroll
    for (int rr = 0; rr < R_; ++rr) a = fmaf(t32[rr], wv_out[rr * H_ + hh], a);
    y[(size_t)m * H_ + hh] = a;
  }
}

extern "C" void kernel_launch(void* const* d_in, const int* in_sizes, int n_in,
                              void* d_out, int out_size, void* d_ws, size_t ws_size,
                              hipStream_t stream) {
  const float* hidden  = (const float*)d_in[0];
  const float* db_keys = (const float*)d_in[1];
  const float* db_vals = (const float*)d_in[2];
  const float* wq_in   = (const float*)d_in[3];
  const float* wq_out  = (const float*)d_in[4];
  const float* wv_in   = (const float*)d_in[5];
  const float* wv_out  = (const float*)d_in[6];
  float* out = (float*)d_out;

  char* ws = (char*)d_ws;
  float*    q      = (float*)(ws + OFF_Q);
  float*    kn     = (float*)(ws + OFF_KN);
  float*    ps     = (float*)(ws + OFF_PS);
  int*      pi     = (int*)  (ws + OFF_PI);
  int*      idx    = (int*)  (ws + OFF_IDX);
  int*      cand   = (int*)  (ws + OFF_CAND);
  float*    kvT    = (float*)(ws + OFF_KVT);
  float*    attout = (float*)(ws + OFF_AO);
  float*    kvV    = (float*)(ws + OFF_KVV);
  ushort_t* dbk16  = (ushort_t*)(ws + OFF_DBK16);

  const size_t need = (size_t)OFF_DBK16 + (size_t)NDB_ * D_ * 2;

  k_compute_q<<<B_ * S_, 256, 0, stream>>>(hidden, wq_in, wq_out, q);
  if (ws_size >= need) {
    // bf16 MFMA candidate path + exact fp32 rescore
    k_kn_cvtT<<<NDB_ / 32, 256, 0, stream>>>(db_keys, kn, dbk16);
    k_knn_mfma<<<512, 256, 0, stream>>>(q, dbk16, kn, ps, pi);
    k_knn_merge16<<<NSEL, 64, 0, stream>>>(ps, pi, cand);
    k_rescore<<<NSEL, 256, 0, stream>>>(q, db_keys, kn, cand, idx);
  } else {
    // fp32 fallback
    k_kn<<<(NDB_ + 3) / 4, 256, 0, stream>>>(db_keys, kn);
    k_knn_partial<<<dim3(NCHUNK, 8), 256, 0, stream>>>(q, db_keys, kn, ps, pi);
    k_knn_merge4<<<NSEL, 64, 0, stream>>>(ps, pi, idx);
  }
  k_gather<<<2 * 64, 256, 0, stream>>>(db_keys, db_vals, idx, kvT, kvV);
  k_attn<<<512, 256, 0, stream>>>(q, kvT, kvV, attout);
  k_out<<<B_ * S_, 256, 0, stream>>>(attout, wv_in, wv_out, out);
}

// Round 3
// 441.415 us; speedup vs baseline: 1.2325x; 1.0230x over previous
//
#include <hip/hip_runtime.h>
#include <cfloat>

// Problem constants (MoMEAdaptor): B=2,S=1024,H=2048,D=256,R=32,K=4,NDB=100000
#define B_   2
#define S_   1024
#define H_   2048
#define D_   256
#define R_   32
#define K_   4
#define NDB_ 100000

// Only queries (b, t<256) feed the attention (mask j<=i => j<1024 => t<256).
#define TSEL 256
#define NSEL (B_ * TSEL)          // 512 queries that need k-NN

// knn tiling: 112 chunks x 896 rows (7 tiles x 128) -> 896 blocks = 3.5 blk/CU
#define NCHUNK     112            // db chunks
#define CHUNK_ROWS 896            // 7 tiles * 128
#define TILES      7
#define NT         128            // db rows per tile
#define MT         64             // queries per block
#define KC         64             // fallback K-chunk
#define LSTR       68             // fallback padded LDS stride

#define NEG_INF  (-3.0e38f)
#define IDX_MAX  0x7fffffff

// attention query tile
#define TQ 4

// Workspace layout (bytes). need = 0xA00000 + 51.2MB (unchanged from r2).
// KVV aliases the dead PS/PI region: ps/pi are consumed by merge16 before
// gather writes kvV (same-stream sequential -> safe, also under graph replay).
#define OFF_Q     0          // 2048*256 f32            (2 MB)
#define OFF_KN    0x200000   // 100000 f32              (400 KB)
#define OFF_PS    0x280000   // 512*112*4 f32 (896 KB)
#define OFF_PI    0x360000   // 512*112*4 i32 (896 KB)
#define OFF_KVV   0x280000   // values dense [2][1024][256] f32 (2 MB) ALIAS ps/pi
#define OFF_KVT   0x480000   // keys transposed [2][256][1024] f32 (2 MB)
#define OFF_AO    0x680000   // attention out [2048][256] f32 (2 MB)
#define OFF_IDX   0x880000   // 2048 i32
#define OFF_CAND  0x890000   // 512*16 i32 candidates
#define OFF_DBK16 0xA00000   // bf16 db copy (MFMA-fragment T-layout) 51.2 MB

typedef unsigned short ushort_t;
typedef unsigned int   uint_t;
typedef __attribute__((ext_vector_type(8)))  __bf16 bf16x8;
typedef __attribute__((ext_vector_type(16))) float  f32x16;

// sorted-insert of (score,idx) into descending top-4; ties -> lower index first
__device__ __forceinline__ void ins4(float sc, int n, float s[4], int id[4]) {
  if (sc > s[3] || (sc == s[3] && n < id[3])) {
    s[3] = sc; id[3] = n;
#pragma unroll
    for (int k = 3; k > 0; --k) {
      if (s[k] > s[k - 1] || (s[k] == s[k - 1] && id[k] < id[k - 1])) {
        float ts = s[k]; s[k] = s[k - 1]; s[k - 1] = ts;
        int ti = id[k]; id[k] = id[k - 1]; id[k - 1] = ti;
      }
    }
  }
}

__device__ __forceinline__ uint_t bfpack(float a, float b) {   // 2x fp32 -> packed bf16 (RNE)
  uint_t ua = __float_as_uint(a), ub = __float_as_uint(b);
  ua = (ua + 0x7fffu + ((ua >> 16) & 1u)) >> 16;
  ub = (ub + 0x7fffu + ((ub >> 16) & 1u)) >> 16;
  return ua | (ub << 16);
}

// ---------------- q = (hidden @ wq_in) @ wq_out,  one block per token ----------------
__global__ __launch_bounds__(256) void k_compute_q(
    const float* __restrict__ hidden, const float* __restrict__ wq_in,
    const float* __restrict__ wq_out, float* __restrict__ q) {
  __shared__ float hrow[H_];
  __shared__ float part[8][R_];
  __shared__ float q1[R_];
  const int m = blockIdx.x;
  const int t = threadIdx.x;
  const float* hp = hidden + (size_t)m * H_;
  ((float4*)hrow)[t]       = ((const float4*)hp)[t];
  ((float4*)hrow)[t + 256] = ((const float4*)hp)[t + 256];
  __syncthreads();
  const int r = t & 31, c = t >> 5;
  float p = 0.f;
#pragma unroll 4
  for (int e = c * 256; e < c * 256 + 256; ++e)
    p = fmaf(hrow[e], wq_in[(size_t)e * R_ + r], p);
  part[c][r] = p;
  __syncthreads();
  if (t < R_) {
    float s = 0.f;
#pragma unroll
    for (int cc = 0; cc < 8; ++cc) s += part[cc][t];
    q1[t] = s;
  }
  __syncthreads();
  float acc = 0.f;
#pragma unroll
  for (int rr = 0; rr < R_; ++rr) acc = fmaf(q1[rr], wq_out[rr * D_ + t], acc);
  q[(size_t)m * D_ + t] = acc;
}

// ------- kn[n] = |db_keys[n]|^2 + bf16 conversion into MFMA-fragment T-layout -------
// T-layout slot (uint4 units): dbk16T[n32*1024 + ks*64 + l] holds bf16 of
// db row (n32*32 + (l&31)), floats [c*8 .. c*8+7], c = 2*ks + (l>>5).
// r2's direct version scattered 16B stores at 2KB stride (TA-serialized).
// Now: LDS-staged transpose. Phase 1 loads 32 rows coalesced into LDS with
// XOR-swizzled 16B slots (slot' = slot ^ (row&7): per-8-lane phase groups hit
// distinct bank groups on both write and read). Phase 2 reads the transpose
// pattern from LDS and emits fully-coalesced 1KB/wave global stores.
__global__ __launch_bounds__(256) void k_kn_cvtT(const float* __restrict__ dbk,
                                                 float* __restrict__ kn,
                                                 ushort_t* __restrict__ dbk16T) {
  __shared__ float sT[32 * 256];         // 32 KB
  const int n32 = blockIdx.x;            // 0..3124 (NDB_/32 exact)
  const int t = threadIdx.x;
  // ---- phase 1: coalesced load + kn ----
  {
    const int r = t >> 3, tc = t & 7;    // row 0..31, 8 threads per row
    const float* rp = dbk + (size_t)(n32 * 32 + r) * D_;
    float s = 0.f;
#pragma unroll
    for (int k = 0; k < 8; ++k) {
      const int sl = tc + 8 * k;         // 16B slot 0..63
      const float4 v = ((const float4*)rp)[sl];
      *(float4*)&sT[(r * 64 + (sl ^ (r & 7))) * 4] = v;
      s += v.x * v.x + v.y * v.y + v.z * v.z + v.w * v.w;
    }
    s += __shfl_down(s, 4, 8);
    s += __shfl_down(s, 2, 8);
    s += __shfl_down(s, 1, 8);
    if (tc == 0) kn[n32 * 32 + r] = s;
  }
  __syncthreads();
  // ---- phase 2: transpose-read + pack + coalesced store ----
  {
    const int l = t & 63, w = t >> 6;
    const int row = l & 31, hc = l >> 5;
    uint4* dst = (uint4*)dbk16T + (size_t)n32 * 1024;
#pragma unroll
    for (int kk = 0; kk < 4; ++kk) {
      const int ks = kk * 4 + w;
      const int c = 2 * ks + hc;         // 8-float chunk 0..31
      const int s0 = (2 * c) ^ (row & 7), s1 = (2 * c + 1) ^ (row & 7);
      const float4 a = *(const float4*)&sT[(row * 64 + s0) * 4];
      const float4 b = *(const float4*)&sT[(row * 64 + s1) * 4];
      uint4 pk;
      pk.x = bfpack(a.x, a.y); pk.y = bfpack(a.z, a.w);
      pk.z = bfpack(b.x, b.y); pk.w = bfpack(b.z, b.w);
      dst[(size_t)ks * 64 + l] = pk;
    }
  }
}

// plain kn (fallback path, no bf16 copy)
__global__ __launch_bounds__(256) void k_kn(const float* __restrict__ dbk,
                                            float* __restrict__ kn) {
  const int w = threadIdx.x >> 6, l = threadIdx.x & 63;
  const int n = blockIdx.x * 4 + w;
  if (n >= NDB_) return;
  const float4 v = ((const float4*)(dbk + (size_t)n * D_))[l];
  float s = v.x * v.x + v.y * v.y + v.z * v.z + v.w * v.w;
#pragma unroll
  for (int off = 32; off; off >>= 1) s += __shfl_down(s, off);
  if (l == 0) kn[n] = s;
}

// ---------------- bf16 MFMA knn: per-(qb, chunk) partial top-4 ----------------
// approx score = 2*(q.k)_bf16 - kn_fp32; final top-4 from exact fp32 rescore.
// SWAPPED operands: acc = mfma(db_frag, q_frag, acc) -> C[n][query], col=lane&31=query.
// Each lane owns 16 scores of ONE query -> register-local top-4; db fragments
// register-streamed from the T-layout copy; ZERO barriers in the main loop.
// r3: chunk split 61x1664 -> 112x896 doubles resident blocks (2 -> 3.5 /CU,
// LDS 36.4KB allows 4) for latency hiding; grid 896, no dummies.
// XCD co-location: chunk%8 == fid%8 -> all 8 qb blocks of a chunk on one XCD.
__global__ __launch_bounds__(256, 4) void k_knn_mfma(
    const float* __restrict__ q, const ushort_t* __restrict__ dbk16T,
    const float* __restrict__ kn, float* __restrict__ pscore,
    int* __restrict__ pidx) {
  __shared__ __align__(16) char smem[32768 + CHUNK_ROWS * 4];
  ushort_t* sA  = (ushort_t*)smem;          // 64 q-rows x 32 chunks x 16B = 32768
  float*    knL = (float*)(smem + 32768);   // kn for this chunk's 896 rows

  const int fid = blockIdx.x;                // 896 blocks
  const int xcd = fid & 7, idx8 = fid >> 3;  // idx8 0..111
  const int chunk = xcd + 8 * (idx8 % 14);   // 0..111, chunk%8==xcd
  const int qb = idx8 / 14;                  // 0..7

  const int tid = threadIdx.x;
  const int wv = tid >> 6, ln = tid & 63;
  const int lm = ln & 31, lh = ln >> 5;
  const int row_base = chunk * CHUNK_ROWS;

  // ---- stage A once: 64 selected q rows -> bf16, swizzled chunks ----
  {
    const int m = tid & 63, cg = tid >> 6;
    const int sq = qb * MT + m;
    const float* qp = q + ((size_t)((sq >> 8) * S_ + (sq & 255))) * D_;
#pragma unroll
    for (int cc = 0; cc < 8; ++cc) {
      const int c = cg * 8 + cc;
      const float4 v0 = *(const float4*)(qp + c * 8);
      const float4 v1 = *(const float4*)(qp + c * 8 + 4);
      uint4 pk;
      pk.x = bfpack(v0.x, v0.y); pk.y = bfpack(v0.z, v0.w);
      pk.z = bfpack(v1.x, v1.y); pk.w = bfpack(v1.z, v1.w);
      *(uint4*)&sA[(m * 32 + (c ^ (m & 7))) * 8] = pk;
    }
  }
  // ---- stage kn for the whole chunk (clamped; OOB rows masked in select) ----
  for (int j = tid; j < CHUNK_ROWS; j += 256) {
    int rr = row_base + j; if (rr >= NDB_) rr = NDB_ - 1;
    knL[j] = kn[rr];
  }
  __syncthreads();   // the ONLY barrier before the final merge

  // per-lane running top-4: acc0 -> query lm, acc1 -> query 32+lm
  float s40[4], s41[4]; int i40[4], i41[4];
#pragma unroll
  for (int k = 0; k < 4; ++k) {
    s40[k] = NEG_INF; i40[k] = IDX_MAX;
    s41[k] = NEG_INF; i41[k] = IDX_MAX;
  }

  const int sw = lm & 7;
  const int abase0 = lm * 32;          // chunk-slot base, query row lm
  const int abase1 = (32 + lm) * 32;   // query row 32+lm (same swizzle)
  const int nbase = wv * 32 + 4 * lh;  // this lane's n_loc base within the tile

  for (int tile = 0; tile < TILES; ++tile) {
    const int row0 = row_base + tile * NT;
    if (row0 >= NDB_) break;
    const int nw = row0 + wv * 32;     // wave's 32-row block (32-aligned)
    if (nw >= NDB_) continue;          // wave-uniform; NDB_ is a multiple of 32

    f32x16 acc0, acc1;
#pragma unroll
    for (int r = 0; r < 16; ++r) { acc0[r] = 0.f; acc1[r] = 0.f; }

    // lane's fragment stream: 16 steps x 1KB coalesced wave reads
    const ushort_t* gw = dbk16T + (size_t)(nw >> 5) * 8192 + (size_t)ln * 8;
#pragma unroll
    for (int ks = 0; ks < 16; ++ks) {
      const bf16x8 bb = *(const bf16x8*)(gw + ks * 512);
      const int cs = (2 * ks + lh) ^ sw;
      const bf16x8 a0 = *(const bf16x8*)&sA[(abase0 + cs) * 8];
      const bf16x8 a1 = *(const bf16x8*)&sA[(abase1 + cs) * 8];
      acc0 = __builtin_amdgcn_mfma_f32_32x32x16_bf16(bb, a0, acc0, 0, 0, 0);
      acc1 = __builtin_amdgcn_mfma_f32_32x32x16_bf16(bb, a1, acc1, 0, 0, 0);
    }

    // ---- register select: lane's 16 n-rows for its two queries ----
#pragma unroll
    for (int g = 0; g < 4; ++g) {
      float v0[4], v1[4]; int nn[4];
#pragma unroll
      for (int j = 0; j < 4; ++j) {
        const int r = g * 4 + j;
        const int off = (r & 3) + 8 * (r >> 2);    // compile-time
        const int nloc = nbase + off;
        const float knv = knL[tile * 128 + nloc];  // LDS broadcast
        const int n = row0 + nloc;
        nn[j] = n;
        const float x0 = fmaf(2.f, acc0[r], -knv);
        const float x1 = fmaf(2.f, acc1[r], -knv);
        const bool ok = n < NDB_;
        v0[j] = ok ? x0 : NEG_INF;
        v1[j] = ok ? x1 : NEG_INF;
      }
      const float m0 = fmaxf(fmaxf(v0[0], v0[1]), fmaxf(v0[2], v0[3]));
      if (m0 >= s40[3]) {
#pragma unroll
        for (int j = 0; j < 4; ++j) ins4(v0[j], nn[j], s40, i40);
      }
      const float m1 = fmaxf(fmaxf(v1[0], v1[1]), fmaxf(v1[2], v1[3]));
      if (m1 >= s41[3]) {
#pragma unroll
        for (int j = 0; j < 4; ++j) ins4(v1[j], nn[j], s41, i41);
      }
    }
  }

  // ---- merge: 8 partial sets per query (4 waves x 2 k-halves) -> top-4 ----
  __syncthreads();
  float* cs = (float*)smem;                 // 64 q x 8 sets x 4 = 8KB
  int*   ci = (int*)(smem + 8192);          // 8KB
  {
    const int st = wv * 2 + lh;
#pragma unroll
    for (int k = 0; k < 4; ++k) {
      cs[(lm * 8 + st) * 4 + k]        = s40[k];
      ci[(lm * 8 + st) * 4 + k]        = i40[k];
      cs[((32 + lm) * 8 + st) * 4 + k] = s41[k];
      ci[((32 + lm) * 8 + st) * 4 + k] = i41[k];
    }
  }
  __syncthreads();
  if (tid < 64) {
    float fs[4]; int fi[4];
#pragma unroll
    for (int k = 0; k < 4; ++k) { fs[k] = NEG_INF; fi[k] = IDX_MAX; }
    for (int c = 0; c < 32; ++c)
      ins4(cs[tid * 32 + c], ci[tid * 32 + c], fs, fi);
    const int sq = qb * MT + tid;
    float* po = pscore + ((size_t)sq * NCHUNK + chunk) * 4;
    int*   io = pidx   + ((size_t)sq * NCHUNK + chunk) * 4;
#pragma unroll
    for (int k = 0; k < 4; ++k) { po[k] = fs[k]; io[k] = fi[k]; }
  }
}

// ---------------- fp32 fallback knn (used if ws too small) ----------------
__global__ __launch_bounds__(256) void k_knn_partial(
    const float* __restrict__ q, const float* __restrict__ dbk,
    const float* __restrict__ kn, float* __restrict__ pscore,
    int* __restrict__ pidx) {
  __shared__ float smem[3 * KC * LSTR];
  float* sA  = smem;
  float* sB0 = smem + KC * LSTR;
  float* sB1 = smem + 2 * KC * LSTR;
  const int tid = threadIdx.x;
  const int tx = tid & 15, ty = tid >> 4;
  const int chunk = blockIdx.x, qb = blockIdx.y;
  const int arq = tid >> 2;
  const int aqd = (tid & 3) * 4;
  const int brk = tid >> 1;
  const int bh  = tid & 1;
  const int bcol = ((brk >> 3) << 2) | (brk & 3);
  float* sBw = (brk & 4) ? sB1 : sB0;
  const int sq_a = qb * MT + arq;
  const float* qsrc = q + ((size_t)((sq_a >> 8) * S_ + (sq_a & 255))) * D_;
  float s4[4][4]; int i4[4][4];
#pragma unroll
  for (int a = 0; a < 4; ++a)
#pragma unroll
    for (int b = 0; b < 4; ++b) { s4[a][b] = NEG_INF; i4[a][b] = IDX_MAX; }
  const int row_base = chunk * CHUNK_ROWS;
  for (int tile = 0; tile < TILES; ++tile) {
    const int row0 = row_base + tile * NT;
    if (row0 >= NDB_) break;
    int krow = row0 + brk; if (krow >= NDB_) krow = NDB_ - 1;
    const float* ksrc = dbk + (size_t)krow * D_;
    float acc[4][8];
#pragma unroll
    for (int a = 0; a < 4; ++a)
#pragma unroll
      for (int b = 0; b < 8; ++b) acc[a][b] = 0.f;
    for (int kc = 0; kc < 4; ++kc) {
      __syncthreads();
#pragma unroll
      for (int p = 0; p < 4; ++p) {
        const int kkl = p * 16 + aqd;
        const float4 v = *(const float4*)(qsrc + kc * KC + kkl);
        sA[(kkl + 0) * LSTR + arq] = v.x;
        sA[(kkl + 1) * LSTR + arq] = v.y;
        sA[(kkl + 2) * LSTR + arq] = v.z;
        sA[(kkl + 3) * LSTR + arq] = v.w;
      }
#pragma unroll
      for (int p = 0; p < 8; ++p) {
        const int kkl = bh * 32 + p * 4;
        const float4 v = *(const float4*)(ksrc + kc * KC + kkl);
        sBw[(kkl + 0) * LSTR + bcol] = v.x;
        sBw[(kkl + 1) * LSTR + bcol] = v.y;
        sBw[(kkl + 2) * LSTR + bcol] = v.z;
        sBw[(kkl + 3) * LSTR + bcol] = v.w;
      }
      __syncthreads();
#pragma unroll 4
      for (int kk = 0; kk < KC; ++kk) {
        const float4 a  = *(const float4*)&sA [kk * LSTR + ty * 4];
        const float4 b0 = *(const float4*)&sB0[kk * LSTR + tx * 4];
        const float4 b1 = *(const float4*)&sB1[kk * LSTR + tx * 4];
        const float av[4] = {a.x, a.y, a.z, a.w};
        const float bv[8] = {b0.x, b0.y, b0.z, b0.w, b1.x, b1.y, b1.z, b1.w};
#pragma unroll
        for (int qi = 0; qi < 4; ++qi)
#pragma unroll
          for (int nj = 0; nj < 8; ++nj)
            acc[qi][nj] = fmaf(av[qi], bv[nj], acc[qi][nj]);
      }
    }
#pragma unroll
    for (int nj = 0; nj < 8; ++nj) {
      const int n = row0 + tx * 8 + nj;
      if (n < NDB_) {
        const float knj = kn[n];
        ins4(2.f * acc[0][nj] - knj, n, s4[0], i4[0]);
        ins4(2.f * acc[1][nj] - knj, n, s4[1], i4[1]);
        ins4(2.f * acc[2][nj] - knj, n, s4[2], i4[2]);
        ins4(2.f * acc[3][nj] - knj, n, s4[3], i4[3]);
      }
    }
  }
  __syncthreads();
  float* cs = smem;
  int*   ci = (int*)(smem + 64 * 65);
#pragma unroll
  for (int qi = 0; qi < 4; ++qi)
#pragma unroll
    for (int k = 0; k < 4; ++k) {
      cs[(ty * 4 + qi) * 65 + tx * 4 + k] = s4[qi][k];
      ci[(ty * 4 + qi) * 65 + tx * 4 + k] = i4[qi][k];
    }
  __syncthreads();
  if (tid < 64) {
    float fs[4]; int fi[4];
#pragma unroll
    for (int k = 0; k < 4; ++k) { fs[k] = NEG_INF; fi[k] = IDX_MAX; }
    for (int c = 0; c < 64; ++c)
      ins4(cs[tid * 65 + c], ci[tid * 65 + c], fs, fi);
    const int sq = qb * MT + tid;
    float* po = pscore + ((size_t)sq * NCHUNK + chunk) * 4;
    int*   io = pidx   + ((size_t)sq * NCHUNK + chunk) * 4;
#pragma unroll
    for (int k = 0; k < 4; ++k) { po[k] = fs[k]; io[k] = fi[k]; }
  }
}

// ---------------- merge chunk candidates -> sorted global top-R ----------------
template <int RANKS>
__device__ __forceinline__ void merge_top(const float* __restrict__ pscore,
                                          const int* __restrict__ pidx,
                                          int* __restrict__ outp) {
  const int sq = blockIdx.x, l = threadIdx.x;
  float s4[4]; int i4[4];
#pragma unroll
  for (int k = 0; k < 4; ++k) { s4[k] = NEG_INF; i4[k] = IDX_MAX; }
  for (int c = l; c < NCHUNK * 4; c += 64)
    ins4(pscore[(size_t)sq * NCHUNK * 4 + c], pidx[(size_t)sq * NCHUNK * 4 + c], s4, i4);
#pragma unroll
  for (int r = 0; r < RANKS; ++r) {
    float s = s4[0]; int i = i4[0];
#pragma unroll
    for (int off = 32; off; off >>= 1) {
      float so = __shfl_down(s, off); int io = __shfl_down(i, off);
      if (so > s || (so == s && io < i)) { s = so; i = io; }
    }
    const float sw = __shfl(s, 0); const int iw = __shfl(i, 0);
    if (l == 0) outp[sq * RANKS + r] = iw;
    if (s4[0] == sw && i4[0] == iw) {
      s4[0] = s4[1]; i4[0] = i4[1];
      s4[1] = s4[2]; i4[1] = i4[2];
      s4[2] = s4[3]; i4[2] = i4[3];
      s4[3] = NEG_INF; i4[3] = IDX_MAX;
    }
  }
}

__global__ __launch_bounds__(64) void k_knn_merge4(const float* __restrict__ ps,
                                                   const int* __restrict__ pi,
                                                   int* __restrict__ knn_idx) {
  merge_top<4>(ps, pi, knn_idx);
}
__global__ __launch_bounds__(64) void k_knn_merge16(const float* __restrict__ ps,
                                                    const int* __restrict__ pi,
                                                    int* __restrict__ cand) {
  merge_top<16>(ps, pi, cand);
}

// ---------------- exact fp32 rescore of 16 candidates -> final sorted top-4 ----------------
__global__ __launch_bounds__(256) void k_rescore(const float* __restrict__ q,
                                                 const float* __restrict__ dbk,
                                                 const float* __restrict__ kn,
                                                 const int* __restrict__ cand,
                                                 int* __restrict__ knn_idx) {
  __shared__ float scs[16];
  __shared__ int   sci[16];
  const int sq = blockIdx.x, wv = threadIdx.x >> 6, l = threadIdx.x & 63;
  const float* qp = q + ((size_t)((sq >> 8) * S_ + (sq & 255))) * D_;
  const float4 qv = ((const float4*)qp)[l];
  for (int cc = wv; cc < 16; cc += 4) {
    const int n = cand[sq * 16 + cc];
    const float4 kv = ((const float4*)(dbk + (size_t)n * D_))[l];
    float s = qv.x * kv.x + qv.y * kv.y + qv.z * kv.z + qv.w * kv.w;
#pragma unroll
    for (int off = 32; off; off >>= 1) s += __shfl_down(s, off);
    if (l == 0) { scs[cc] = 2.f * s - kn[n]; sci[cc] = n; }
  }
  __syncthreads();
  if (threadIdx.x == 0) {
    float s4[4]; int i4[4];
#pragma unroll
    for (int k = 0; k < 4; ++k) { s4[k] = NEG_INF; i4[k] = IDX_MAX; }
#pragma unroll
    for (int c = 0; c < 16; ++c) ins4(scs[c], sci[c], s4, i4);
#pragma unroll
    for (int k = 0; k < 4; ++k) knn_idx[sq * 4 + k] = i4[k];
  }
}

// -------- gather: keys transposed kvT[b][d][j] + values dense kvV[b][j][d] --------
__global__ __launch_bounds__(256) void k_gather(const float* __restrict__ dbk,
                                                const float* __restrict__ dbv,
                                                const int* __restrict__ knn_idx,
                                                float* __restrict__ kvT,
                                                float* __restrict__ kvV) {
  const int b = blockIdx.x >> 6, j0 = (blockIdx.x & 63) * 16;
  const int w = threadIdx.x >> 6, l = threadIdx.x & 63;
  float* dstT = kvT + (size_t)b * D_ * 1024;
  float* dstV = kvV + (size_t)b * 1024 * D_;
  for (int jj = w; jj < 16; jj += 4) {
    const int j = j0 + jj;
    const int row = knn_idx[b * 1024 + j];
    const float4 kv = ((const float4*)(dbk + (size_t)row * D_))[l];
    dstT[(4 * l + 0) * 1024 + j] = kv.x;
    dstT[(4 * l + 1) * 1024 + j] = kv.y;
    dstT[(4 * l + 2) * 1024 + j] = kv.z;
    dstT[(4 * l + 3) * 1024 + j] = kv.w;
    const float4 vv = ((const float4*)(dbv + (size_t)row * D_))[l];
    ((float4*)(dstV + (size_t)j * D_))[l] = vv;
  }
}

// ---------------- attention: TQ=4 queries per block, K/V reads shared ----------------
template <int CMAX>
__device__ __forceinline__ void qk_dots(const float* __restrict__ kb, int t,
                                        const float (*qrow)[D_], float a[4][TQ]) {
#pragma unroll 2
  for (int d = 0; d < D_; d += 4) {
    float qv[TQ][4];
#pragma unroll
    for (int q = 0; q < TQ; ++q) {
      const float4 v = *(const float4*)&qrow[q][d];
      qv[q][0] = v.x; qv[q][1] = v.y; qv[q][2] = v.z; qv[q][3] = v.w;
    }
#pragma unroll
    for (int dd = 0; dd < 4; ++dd) {
      float kv[CMAX];
#pragma unroll
      for (int c = 0; c < CMAX; ++c)
        kv[c] = kb[(size_t)(d + dd) * 1024 + c * 256 + t];
#pragma unroll
      for (int c = 0; c < CMAX; ++c)
#pragma unroll
        for (int q = 0; q < TQ; ++q)
          a[c][q] = fmaf(qv[q][dd], kv[c], a[c][q]);
    }
  }
}

__global__ __launch_bounds__(256) void k_attn(const float* __restrict__ qarr,
                                              const float* __restrict__ kvT,
                                              const float* __restrict__ kvV,
                                              float* __restrict__ attout) {
  __shared__ float qrow[TQ][D_];       // 4 KB (pre-scaled)
  __shared__ float attw[TQ][1024];     // 16 KB softmax weights
  __shared__ float pvred[4][TQ][D_];   // 16 KB wave-partial PV
  __shared__ float redm[4][TQ], reds[4][TQ];

  const int fid = blockIdx.x;          // 512 blocks
  const int b = fid & 1;               // batch parity == XCD parity
  const int g = fid >> 1;              // 0..255
  const int h = g >> 1;
  const int grp = (g & 1) ? (255 - h) : h;   // heavy/light fold
  const int i0 = grp * TQ;
  const int t = threadIdx.x;
  const int w = t >> 6, l = t & 63;
  const int nkmax = i0 + TQ;           // rows needed (query i0+3 has nk=i0+4)
  const int cmax = (nkmax + 255) >> 8;

  // load TQ q rows, pre-scaled by 1/sqrt(D)=0.0625
  {
    const float4 v = ((const float4*)(qarr + ((size_t)b * S_ + i0 + w) * D_))[l];
    float4 sv;
    sv.x = v.x * 0.0625f; sv.y = v.y * 0.0625f;
    sv.z = v.z * 0.0625f; sv.w = v.w * 0.0625f;
    ((float4*)&qrow[w][0])[l] = sv;
  }
  __syncthreads();

  // ---- QK: thread t owns key column j = c*256+t across up to cmax chunks ----
  const float* kb = kvT + (size_t)b * D_ * 1024;
  float a[4][TQ];
#pragma unroll
  for (int c = 0; c < 4; ++c)
#pragma unroll
    for (int q = 0; q < TQ; ++q) a[c][q] = 0.f;
  switch (cmax) {
    case 1: qk_dots<1>(kb, t, qrow, a); break;
    case 2: qk_dots<2>(kb, t, qrow, a); break;
    case 3: qk_dots<3>(kb, t, qrow, a); break;
    default: qk_dots<4>(kb, t, qrow, a); break;
  }
  // causal mask: key j valid for query i0+q iff j <= i0+q
#pragma unroll
  for (int c = 0; c < 4; ++c)
    if (c < cmax)
#pragma unroll
      for (int q = 0; q < TQ; ++q)
        if (c * 256 + t > i0 + q) a[c][q] = NEG_INF;

  // ---- softmax (per query): max, exp, sum, normalize into attw ----
  float M[TQ];
#pragma unroll
  for (int q = 0; q < TQ; ++q) {
    float m = NEG_INF;
    for (int c = 0; c < cmax; ++c) m = fmaxf(m, a[c][q]);
#pragma unroll
    for (int off = 32; off; off >>= 1) m = fmaxf(m, __shfl_down(m, off));
    if (l == 0) redm[w][q] = m;
  }
  __syncthreads();
#pragma unroll
  for (int q = 0; q < TQ; ++q)
    M[q] = fmaxf(fmaxf(redm[0][q], redm[1][q]), fmaxf(redm[2][q], redm[3][q]));
  float inv[TQ];
#pragma unroll
  for (int q = 0; q < TQ; ++q) {
    float s = 0.f;
    for (int c = 0; c < cmax; ++c) {
      const float p = (a[c][q] > 0.5f * NEG_INF) ? __expf(a[c][q] - M[q]) : 0.f;
      a[c][q] = p; s += p;
    }
#pragma unroll
    for (int off = 32; off; off >>= 1) s += __shfl_down(s, off);
    if (l == 0) reds[w][q] = s;
  }
  __syncthreads();
#pragma unroll
  for (int q = 0; q < TQ; ++q)
    inv[q] = 1.f / (reds[0][q] + reds[1][q] + reds[2][q] + reds[3][q]);
  for (int c = 0; c < cmax; ++c)
#pragma unroll
    for (int q = 0; q < TQ; ++q)
      attw[q][c * 256 + t] = a[c][q] * inv[q];
  __syncthreads();

  // ---- PV: wave w handles rows j == w (mod 4); lane l owns d = 4l..4l+3 ----
  const float* vb = kvV + (size_t)b * 1024 * D_;
  float4 acc[TQ];
#pragma unroll
  for (int q = 0; q < TQ; ++q) acc[q] = make_float4(0.f, 0.f, 0.f, 0.f);
#pragma unroll 2
  for (int j = w; j < nkmax; j += 4) {
    const float4 v = ((const float4*)(vb + (size_t)j * D_))[l];
#pragma unroll
    for (int q = 0; q < TQ; ++q) {
      const float p = attw[q][j];        // LDS broadcast (uniform addr)
      acc[q].x = fmaf(p, v.x, acc[q].x);
      acc[q].y = fmaf(p, v.y, acc[q].y);
      acc[q].z = fmaf(p, v.z, acc[q].z);
      acc[q].w = fmaf(p, v.w, acc[q].w);
    }
  }
#pragma unroll
  for (int q = 0; q < TQ; ++q) ((float4*)&pvred[w][q][0])[l] = acc[q];
  __syncthreads();
  {
    const int q = t >> 6;                // 256 threads = 4 q x 64 lanes
    float4 s = make_float4(0.f, 0.f, 0.f, 0.f);
#pragma unroll
    for (int ww = 0; ww < 4; ++ww) {
      const float4 p = ((const float4*)&pvred[ww][q][0])[l];
      s.x += p.x; s.y += p.y; s.z += p.z; s.w += p.w;
    }
    ((float4*)(attout + ((size_t)b * S_ + i0 + q) * D_))[l] = s;
  }
}

// ---------------- y = (attout @ wv_in) @ wv_out, one block per token ----------------
__global__ __launch_bounds__(256) void k_out(const float* __restrict__ attout,
                                             const float* __restrict__ wv_in,
                                             const float* __restrict__ wv_out,
                                             float* __restrict__ y) {
  __shared__ float row[D_];
  __shared__ float part[8][R_];
  __shared__ float t32[R_];
  const int m = blockIdx.x, t = threadIdx.x;
  row[t] = attout[(size_t)m * D_ + t];
  __syncthreads();
  const int r = t & 31, c = t >> 5;
  float p = 0.f;
#pragma unroll
  for (int d = c * 32; d < c * 32 + 32; ++d)
    p = fmaf(row[d], wv_in[d * R_ + r], p);
  part[c][r] = p;
  __syncthreads();
  if (t < R_) {
    float s = 0.f;
#pragma unroll
    for (int cc = 0; cc < 8; ++cc) s += part[cc][t];
    t32[t] = s;
  }
  __syncthreads();
  for (int hh = t; hh < H_; hh += 256) {
    float a = 0.f;
#pragma unroll
    for (int rr = 0; rr < R_; ++rr) a = fmaf(t32[rr], wv_out[rr * H_ + hh], a);
    y[(size_t)m * H_ + hh] = a;
  }
}

extern "C" void kernel_launch(void* const* d_in, const int* in_sizes, int n_in,
                              void* d_out, int out_size, void* d_ws, size_t ws_size,
                              hipStream_t stream) {
  const float* hidden  = (const float*)d_in[0];
  const float* db_keys = (const float*)d_in[1];
  const float* db_vals = (const float*)d_in[2];
  const float* wq_in   = (const float*)d_in[3];
  const float* wq_out  = (const float*)d_in[4];
  const float* wv_in   = (const float*)d_in[5];
  const float* wv_out  = (const float*)d_in[6];
  float* out = (float*)d_out;

  char* ws = (char*)d_ws;
  float*    q      = (float*)(ws + OFF_Q);
  float*    kn     = (float*)(ws + OFF_KN);
  float*    ps     = (float*)(ws + OFF_PS);
  int*      pi     = (int*)  (ws + OFF_PI);
  int*      idx    = (int*)  (ws + OFF_IDX);
  int*      cand   = (int*)  (ws + OFF_CAND);
  float*    kvT    = (float*)(ws + OFF_KVT);
  float*    attout = (float*)(ws + OFF_AO);
  float*    kvV    = (float*)(ws + OFF_KVV);
  ushort_t* dbk16  = (ushort_t*)(ws + OFF_DBK16);

  const size_t need = (size_t)OFF_DBK16 + (size_t)NDB_ * D_ * 2;

  k_compute_q<<<B_ * S_, 256, 0, stream>>>(hidden, wq_in, wq_out, q);
  if (ws_size >= need) {
    // bf16 MFMA candidate path + exact fp32 rescore
    k_kn_cvtT<<<NDB_ / 32, 256, 0, stream>>>(db_keys, kn, dbk16);
    k_knn_mfma<<<NCHUNK * 8, 256, 0, stream>>>(q, dbk16, kn, ps, pi);
    k_knn_merge16<<<NSEL, 64, 0, stream>>>(ps, pi, cand);
    k_rescore<<<NSEL, 256, 0, stream>>>(q, db_keys, kn, cand, idx);
  } else {
    // fp32 fallback
    k_kn<<<(NDB_ + 3) / 4, 256, 0, stream>>>(db_keys, kn);
    k_knn_partial<<<dim3(NCHUNK, 8), 256, 0, stream>>>(q, db_keys, kn, ps, pi);
    k_knn_merge4<<<NSEL, 64, 0, stream>>>(ps, pi, idx);
  }
  k_gather<<<2 * 64, 256, 0, stream>>>(db_keys, db_vals, idx, kvT, kvV);
  k_attn<<<512, 256, 0, stream>>>(q, kvT, kvV, attout);
  k_out<<<B_ * S_, 256, 0, stream>>>(attout, wv_in, wv_out, out);
}